// Round 4
// baseline (2007.636 us; speedup 1.0000x reference)
//
#include <hip/hip_runtime.h>

// DCGRU cell, MI355X gfx950.  N=4096, B=64, IN_DIM=2, UNITS=64, K=2, NSUP=2,
// M=5, IN_SZ=66.  Heavy: 8x GEMM Y(4096x4224)=S(4096x4096)@X, bf16 MFMA.
// GEMM v3: 128x256 tile, BK=32, 8 waves (2Mx4N, wave-tile 64x64, acc[4][4]
// = 64 AGPR), LDS 48KB double-buffered -> 2 blocks/CU (16 waves/CU) for
// cross-block latency hiding AND round-packing (grid 544/1088 over 512
// block slots).  LDS uses a paired-line layout: tile [R][32] bf16 stored as
// R/2 lines of 128B = {row r | row r+R/2}, 16B slot ^= (line&7) -> every
// ds_read_b128 is uniform 2-way (free); global_load_lds keeps a linear
// dest, the inverse permutation is applied to the per-lane global SOURCE.
// Counted-prefetch: tile t+1 staged during tile t, vmcnt(0) only at tile
// end.  XCD chunk swizzle (grids % 8 == 0).  g2+g3 fused via blockIdx.z.
// (Resubmission of R2 source: R2 bench died to an infra failure, no data.)

typedef unsigned short u16;
typedef unsigned int u32;
typedef __attribute__((ext_vector_type(8))) short short8;   // bf16x8 MFMA frag
typedef __attribute__((ext_vector_type(4))) float floatx4;  // MFMA acc
typedef __attribute__((ext_vector_type(4))) u16 u16x4;

__device__ __forceinline__ u16 f2b(float f) {            // fp32 -> bf16 RNE
    u32 x = __float_as_uint(f);
    return (u16)((x + 0x7fffu + ((x >> 16) & 1u)) >> 16);
}
__device__ __forceinline__ float b2f(u16 u) {
    return __uint_as_float(((u32)u) << 16);
}

// async global->LDS, 16B per lane; LDS dest = wave-uniform base + lane*16
#define GLL16(g, l) __builtin_amdgcn_global_load_lds( \
    (const __attribute__((address_space(1))) void*)(g), \
    (__attribute__((address_space(3))) void*)(l), 16, 0, 0)

// ---------------------------------------------------------------- cvt fp32->bf16
__global__ void cvt_bf16_kernel(const float* __restrict__ src, u16* __restrict__ dst) {
    size_t i = ((size_t)blockIdx.x * 256 + threadIdx.x) * 4;
    floatx4 v = *(const floatx4*)&src[i];
    u16x4 p; p[0] = f2b(v[0]); p[1] = f2b(v[1]); p[2] = f2b(v[2]); p[3] = f2b(v[3]);
    *(u16x4*)&dst[i] = p;
}

// ------------------------------------------- x0T rows 0..127  (c=0,1 from inputs)
__global__ void build_x0_inputs(const float* __restrict__ inp, u16* __restrict__ x0T) {
    const int row = blockIdx.x;           // 0..127
    const int c = row >> 6, b = row & 63;
    const int t = threadIdx.x;
    const int n0 = t * 16;
    u16* dst = x0T + (size_t)row * 4096 + n0;
    #pragma unroll
    for (int g = 0; g < 4; ++g) {
        u16x4 pk;
        #pragma unroll
        for (int e = 0; e < 4; ++e) {
            const float* p = &inp[(size_t)b * 8192 + (size_t)(n0 + g * 4 + e) * 2];
            pk[e] = f2b(c ? p[1] : p[0]);
        }
        *(u16x4*)(dst + g * 4) = pk;
    }
}

// ----------------------------- x0T rows 128..4223 from state (hx):  transpose
__global__ void build_x0_state(const float* __restrict__ st, u16* __restrict__ x0T) {
    __shared__ float lds[64 * 68];
    const int t = threadIdx.x;
    const int n0 = blockIdx.x * 64, b = blockIdx.y;
    const float* src = st + (size_t)b * 262144 + (size_t)n0 * 64;
    #pragma unroll
    for (int r = 0; r < 4; ++r) {
        int i = r * 1024 + t * 4;
        floatx4 v = *(const floatx4*)&src[i];
        int nl = i >> 6, j = i & 63;
        *(floatx4*)&lds[nl * 68 + j] = v;
    }
    __syncthreads();
    const int j = t >> 2, q = t & 3;
    u16* dst = x0T + (size_t)((j + 2) * 64 + b) * 4096 + n0 + q * 16;
    #pragma unroll
    for (int g = 0; g < 4; ++g) {
        u16x4 pk;
        #pragma unroll
        for (int e = 0; e < 4; ++e) pk[e] = f2b(lds[(q * 16 + g * 4 + e) * 68 + j]);
        *(u16x4*)(dst + g * 4) = pk;
    }
}

// -------------------------------------------- W^T prep: WT[o][k] bf16, k pad 384
__global__ void wt_prep(const float* __restrict__ W, u16* __restrict__ WT, int O) {
    int idx = blockIdx.x * 256 + threadIdx.x;   // o*384 + k
    int o = idx / 384, k = idx - o * 384;
    if (o < O) WT[idx] = (k < 330) ? f2b(W[(size_t)k * O + o]) : (u16)0;
}

// --------------------------------------------------------------- bf16 MFMA GEMM
// C[m][col] = sum_k A[m][k]*B[col][k]; store YT[col][m]; Y = 2*C - Z if Z.
// Tile 128(M) x 256(N) x K=32 per iter, 128 iters.  8 waves: wr = wave>>2
// (M-half of 128), wc = wave&3 (N-quarter of 256); wave-tile 64x64.
// LDS (48KB, x2 buffers at 0/24576): A region 8KB (64 lines), B region
// 16KB (128 lines) at +8192.  Line pairing: A row r -> line r&63, half
// r>>6; B row r -> line r&127, half r>>7.  Byte addr within region:
// line*128 + ((half*4 + kgrp) ^ (line&7))*16 + (k&7)*2, kgrp = k>>3.
// Staging (global_load_lds, linear dest): thread t writes dest bytes
// t*16..+15; line = t>>3 (+64 for B round 1), stored slot = t&7,
// logical sl = (t&7)^(line&7) -> src row = (sl>>2)*half + line,
// src col = (sl&3)*8.  All reads are uniform 2-way bank aliased (free).
__global__ __launch_bounds__(512, 4) void gemm128_kernel(
        const u16* __restrict__ Aa, const u16* __restrict__ Ab,
        const u16* __restrict__ Bp,
        u16* __restrict__ Ya, u16* __restrict__ Yb,
        const u16* __restrict__ Za, const u16* __restrict__ Zb) {
    __shared__ __align__(128) char sm[49152];
    // ---- XCD chunk swizzle (bijective; 544 and 1088 are % 8 == 0)
    const int nwg = 544 * (int)gridDim.z;
    const int L = (int)blockIdx.x + ((int)blockIdx.y << 5) + (int)blockIdx.z * 544;
    const int vid = (L & 7) * (nwg >> 3) + (L >> 3);
    const int z = vid / 544;
    const int r = vid - z * 544;
    const int rb = r & 31, cb = r >> 5;
    const u16* A = z ? Ab : Aa;
    u16*       Y = z ? Yb : Ya;
    const u16* Z = z ? Zb : Za;

    const int t = threadIdx.x;
    const int lane = t & 63, wave = t >> 6;
    const int m16 = lane & 15, quad = lane >> 4;
    const int wr = wave >> 2, wc = wave & 3;

    // ---- staging source (inverse paired-line permutation), linear LDS dest
    const int tl = t >> 3, ts = t & 7;
    const int sa = ts ^ (tl & 7);
    const int rowA = ((sa >> 2) << 6) + tl;          // 0..127
    const int rowB = ((sa >> 2) << 7) + tl;          // 0..63 / 128..191
    const int colS = (sa & 3) << 3;
    const u16* aS  = A  + ((size_t)rb * 128 + rowA) * 4096 + colS;
    const u16* bS0 = Bp + ((size_t)cb * 256 + rowB) * 4096 + colS;
    const u16* bS1 = bS0 + (size_t)64 * 4096;        // B lines 64..127
    const int wl = wave << 10;                       // wave-uniform GLL dest

    // ---- ds_read bases (paired-line addressing)
    const int sx = m16 & 7;
    const char* smA = sm + m16 * 128 + ((((wr << 2) | quad) ^ sx) << 4);
    const char* smB = sm + 8192 + (((wc & 1) << 6) + m16) * 128
                         + ((((wc >> 1) << 2 | quad) ^ sx) << 4);

    floatx4 acc[4][4];
    #pragma unroll
    for (int i = 0; i < 4; ++i)
        #pragma unroll
        for (int j = 0; j < 4; ++j) acc[i][j] = (floatx4)0.f;

    // ---- prologue: tile 0 -> buf0
    GLL16(aS,  sm + 0     + wl);
    GLL16(bS0, sm + 8192  + wl);
    GLL16(bS1, sm + 16384 + wl);
    asm volatile("s_waitcnt vmcnt(0)" ::: "memory");
    __builtin_amdgcn_s_barrier();

    for (int tt = 0; tt < 128; ++tt) {
        const int P = (tt & 1) * 24576;
        const int Q = P ^ 24576;
        const int ko = ((tt + 1) & 127) << 5;        // wraps on last iter (quarantined)
        // prefetch tile t+1 into Q (DMA overlaps this tile's compute)
        GLL16(aS  + ko, sm + Q + 0     + wl);
        GLL16(bS0 + ko, sm + Q + 8192  + wl);
        GLL16(bS1 + ko, sm + Q + 16384 + wl);
        // fragments of tile t from P
        short8 af[4], bf[4];
        #pragma unroll
        for (int i = 0; i < 4; ++i) af[i] = *(const short8*)(smA + P + i * 2048);
        #pragma unroll
        for (int j = 0; j < 4; ++j) bf[j] = *(const short8*)(smB + P + j * 2048);
        asm volatile("s_waitcnt lgkmcnt(0)" ::: "memory");
        __builtin_amdgcn_sched_barrier(0);
        __builtin_amdgcn_s_setprio(1);
        #pragma unroll
        for (int i = 0; i < 4; ++i)
            #pragma unroll
            for (int j = 0; j < 4; ++j)
                acc[i][j] = __builtin_amdgcn_mfma_f32_16x16x32_bf16(af[i], bf[j], acc[i][j], 0, 0, 0);
        __builtin_amdgcn_s_setprio(0);
        asm volatile("s_waitcnt vmcnt(0)" ::: "memory");   // t+1 resident
        __builtin_amdgcn_s_barrier();
    }

    // ---- epilogue: C (+ optional 2*C - Z) -> YT[col][row] bf16
    #pragma unroll
    for (int i = 0; i < 4; ++i) {
        const int row = rb * 128 + wr * 64 + i * 16 + quad * 4;
        #pragma unroll
        for (int j = 0; j < 4; ++j) {
            const int col = cb * 256 + wc * 64 + j * 16 + m16;
            const size_t off = (size_t)col * 4096 + row;
            floatx4 v = acc[i][j];
            if (Z) {
                u16x4 zz = *(const u16x4*)(Z + off);
                #pragma unroll
                for (int e = 0; e < 4; ++e) v[e] = 2.f * v[e] - b2f(zz[e]);
            }
            u16x4 pk;
            #pragma unroll
            for (int e = 0; e < 4; ++e) pk[e] = f2b(v[e]);
            *(u16x4*)(Y + off) = pk;
        }
    }
}

// --------------------------------------------------------- proj helpers (X rows)
__device__ __forceinline__ const u16* xrow(int k, int b,
        const u16* x0, const u16* y1, const u16* y2, const u16* y3, const u16* y4) {
    int c = (int)((unsigned)k / 5u);
    int m = k - c * 5;
    if (c > 65) c = 65;                       // pad region: clamp in-bounds (W=0 there)
    const u16* base = (m == 0) ? x0 : (m == 1) ? y1 : (m == 2) ? y2 : (m == 3) ? y3 : y4;
    return base + (size_t)(c * 64 + b) * 4096;
}

__device__ __forceinline__ void ilv(uint4 a, uint4 b, u32* w) {
    // a = 8 bf16 of row k, b = 8 bf16 of row k+1 -> 8 words (k|k+1<<16) per bn
    const u32* ap = (const u32*)&a; const u32* bp = (const u32*)&b;
    #pragma unroll
    for (int i = 0; i < 4; ++i) {
        u32 x = ap[i], y = bp[i];
        w[2 * i]     = (x & 0xffffu) | (y << 16);
        w[2 * i + 1] = (x >> 16) | (y & 0xffff0000u);
    }
}

// ------------------------------------------------- proj fn: MFMA GEMM + gates
__global__ __launch_bounds__(256, 2) void proj_fn_kernel(
        const u16* __restrict__ x0T, const u16* __restrict__ y1T,
        const u16* __restrict__ y2T, const u16* __restrict__ y3T,
        const u16* __restrict__ y4T,
        const u16* __restrict__ WT, const float* __restrict__ bias,
        const float* __restrict__ hx,
        u16* __restrict__ u_t, u16* __restrict__ x0Tw) {
    __shared__ __align__(16) u32 Xs[32 * 132];   // [kp][bn] interleaved, 16.9 KB
    __shared__ __align__(16) u16 Ws[128 * 72];   // [o][k] pad 72, 18.4 KB
    const int t = threadIdx.x;
    const int lane = t & 63, wave = t >> 6;
    const int m16 = lane & 15, quad = lane >> 4;
    const int wr = wave >> 1, wc = wave & 1;
    const int n0 = blockIdx.x * 128, b = blockIdx.y;

    const int kp = t >> 3, sgx = t & 7;          // X staging: kp 0..31, 16 n per sgx
    const int wrow = t >> 1, whalf = t & 1;      // W staging

    floatx4 acc[4][4];
    #pragma unroll
    for (int i = 0; i < 4; ++i)
        #pragma unroll
        for (int j = 0; j < 4; ++j) acc[i][j] = (floatx4)0.f;

    for (int ki = 0; ki < 6; ++ki) {
        const int k0 = ki * 64;
        const u16* pa = xrow(k0 + 2 * kp,     b, x0T, y1T, y2T, y3T, y4T) + n0 + sgx * 16;
        const u16* pb = xrow(k0 + 2 * kp + 1, b, x0T, y1T, y2T, y3T, y4T) + n0 + sgx * 16;
        uint4 a0 = *(const uint4*)pa;
        uint4 a1 = *(const uint4*)(pa + 8);
        uint4 b0 = *(const uint4*)pb;
        uint4 b1 = *(const uint4*)(pb + 8);
        const u16* wsrc = WT + (size_t)wrow * 384 + k0 + whalf * 32;
        uint4 wv[4];
        #pragma unroll
        for (int q = 0; q < 4; ++q) wv[q] = *(const uint4*)(wsrc + q * 8);

        u32 w[16];
        ilv(a0, b0, w);
        ilv(a1, b1, w + 8);
        __syncthreads();                          // prev tile reads done
        u32* xdst = &Xs[kp * 132 + sgx * 16];
        #pragma unroll
        for (int q = 0; q < 4; ++q) *(uint4*)(xdst + q * 4) = *(uint4*)(w + q * 4);
        uint4* wdst = (uint4*)&Ws[wrow * 72 + whalf * 32];
        #pragma unroll
        for (int q = 0; q < 4; ++q) wdst[q] = wv[q];
        __syncthreads();

        #pragma unroll
        for (int ks = 0; ks < 2; ++ks) {
            short8 af[4], bf[4];
            #pragma unroll
            for (int i = 0; i < 4; ++i)
                af[i] = *(const short8*)&Ws[(wr * 64 + i * 16 + m16) * 72 + ks * 32 + quad * 8];
            #pragma unroll
            for (int j = 0; j < 4; ++j) {
                const u32* xp = &Xs[(ks * 16 + quad * 4) * 132 + wc * 64 + j * 16 + m16];
                union { uint4 u; short8 s; } fu;
                fu.u.x = xp[0]; fu.u.y = xp[132]; fu.u.z = xp[264]; fu.u.w = xp[396];
                bf[j] = fu.s;
            }
            #pragma unroll
            for (int i = 0; i < 4; ++i)
                #pragma unroll
                for (int j = 0; j < 4; ++j)
                    acc[i][j] = __builtin_amdgcn_mfma_f32_16x16x32_bf16(af[i], bf[j], acc[i][j], 0, 0, 0);
        }
    }
    // epilogue
    #pragma unroll
    for (int i = 0; i < 4; ++i) {
        const int o0 = wr * 64 + i * 16 + quad * 4;
        floatx4 bz = *(const floatx4*)&bias[o0];
        #pragma unroll
        for (int j = 0; j < 4; ++j) {
            const int bnl = wc * 64 + j * 16 + m16;
            const size_t bn = (size_t)b * 4096 + n0 + bnl;
            floatx4 v = acc[i][j];
            float s[4];
            #pragma unroll
            for (int e = 0; e < 4; ++e) s[e] = 1.f / (1.f + __expf(-(v[e] + bz[e])));
            if (wr == 0) {          // r -> x0T state rows: bf16(r*hx)
                floatx4 hv = *(const floatx4*)&hx[bn * 64 + o0];
                #pragma unroll
                for (int e = 0; e < 4; ++e)
                    x0Tw[(size_t)((o0 + e + 2) * 64 + b) * 4096 + (n0 + bnl)] = f2b(s[e] * hv[e]);
            } else {                // u -> u_t[bn][o-64]
                u16x4 pk;
                #pragma unroll
                for (int e = 0; e < 4; ++e) pk[e] = f2b(s[e]);
                *(u16x4*)&u_t[bn * 64 + (o0 - 64)] = pk;
            }
        }
    }
}

// --------------------------------------- proj g: MFMA GEMM + tanh + GRU output
__global__ __launch_bounds__(256, 2) void proj_g_kernel(
        const u16* __restrict__ x0T, const u16* __restrict__ y1T,
        const u16* __restrict__ y2T, const u16* __restrict__ y3T,
        const u16* __restrict__ y4T,
        const u16* __restrict__ WT, const float* __restrict__ bias,
        const float* __restrict__ hx, const u16* __restrict__ u_t,
        float* __restrict__ out) {
    __shared__ __align__(16) u32 Xs[32 * 132];
    __shared__ __align__(16) u16 Ws[64 * 72];
    const int t = threadIdx.x;
    const int lane = t & 63, wave = t >> 6;
    const int m16 = lane & 15, quad = lane >> 4;
    const int wr = wave >> 1, wc = wave & 1;
    const int n0 = blockIdx.x * 128, b = blockIdx.y;

    const int kp = t >> 3, sgx = t & 7;
    const int wrow = t >> 2, wq = t & 3;

    floatx4 acc[2][4];
    #pragma unroll
    for (int i = 0; i < 2; ++i)
        #pragma unroll
        for (int j = 0; j < 4; ++j) acc[i][j] = (floatx4)0.f;

    for (int ki = 0; ki < 6; ++ki) {
        const int k0 = ki * 64;
        const u16* pa = xrow(k0 + 2 * kp,     b, x0T, y1T, y2T, y3T, y4T) + n0 + sgx * 16;
        const u16* pb = xrow(k0 + 2 * kp + 1, b, x0T, y1T, y2T, y3T, y4T) + n0 + sgx * 16;
        uint4 a0 = *(const uint4*)pa;
        uint4 a1 = *(const uint4*)(pa + 8);
        uint4 b0 = *(const uint4*)pb;
        uint4 b1 = *(const uint4*)(pb + 8);
        const u16* wsrc = WT + (size_t)wrow * 384 + k0 + wq * 16;
        uint4 w0 = *(const uint4*)wsrc;
        uint4 w1 = *(const uint4*)(wsrc + 8);

        u32 w[16];
        ilv(a0, b0, w);
        ilv(a1, b1, w + 8);
        __syncthreads();
        u32* xdst = &Xs[kp * 132 + sgx * 16];
        #pragma unroll
        for (int q = 0; q < 4; ++q) *(uint4*)(xdst + q * 4) = *(uint4*)(w + q * 4);
        *(uint4*)&Ws[wrow * 72 + wq * 16] = w0;
        *(uint4*)&Ws[wrow * 72 + wq * 16 + 8] = w1;
        __syncthreads();

        #pragma unroll
        for (int ks = 0; ks < 2; ++ks) {
            short8 af[2], bf[4];
            #pragma unroll
            for (int i = 0; i < 2; ++i)
                af[i] = *(const short8*)&Ws[(wr * 32 + i * 16 + m16) * 72 + ks * 32 + quad * 8];
            #pragma unroll
            for (int j = 0; j < 4; ++j) {
                const u32* xp = &Xs[(ks * 16 + quad * 4) * 132 + wc * 64 + j * 16 + m16];
                union { uint4 u; short8 s; } fu;
                fu.u.x = xp[0]; fu.u.y = xp[132]; fu.u.z = xp[264]; fu.u.w = xp[396];
                bf[j] = fu.s;
            }
            #pragma unroll
            for (int i = 0; i < 2; ++i)
                #pragma unroll
                for (int j = 0; j < 4; ++j)
                    acc[i][j] = __builtin_amdgcn_mfma_f32_16x16x32_bf16(af[i], bf[j], acc[i][j], 0, 0, 0);
        }
    }
    #pragma unroll
    for (int i = 0; i < 2; ++i) {
        const int o0 = wr * 32 + i * 16 + quad * 4;
        floatx4 bz = *(const floatx4*)&bias[o0];
        #pragma unroll
        for (int j = 0; j < 4; ++j) {
            const int bnl = wc * 64 + j * 16 + m16;
            const size_t bn = (size_t)b * 4096 + n0 + bnl;
            floatx4 v = acc[i][j];
            u16x4 uu = *(const u16x4*)&u_t[bn * 64 + o0];
            floatx4 hv = *(const floatx4*)&hx[bn * 64 + o0];
            floatx4 ov;
            #pragma unroll
            for (int e = 0; e < 4; ++e) {
                float c = tanhf(v[e] + bz[e]);
                float u = b2f(uu[e]);
                ov[e] = u * hv[e] + (1.f - u) * c;
            }
            *(floatx4*)&out[bn * 64 + o0] = ov;
        }
    }
}

// --------------------------------------------------------------------- launch
extern "C" void kernel_launch(void* const* d_in, const int* in_sizes, int n_in,
                              void* d_out, int out_size, void* d_ws, size_t ws_size,
                              hipStream_t stream) {
    (void)in_sizes; (void)n_in; (void)out_size; (void)ws_size;
    const float* inputs   = (const float*)d_in[0];
    const float* hx       = (const float*)d_in[1];
    const float* supports = (const float*)d_in[2];
    const float* w_fn     = (const float*)d_in[3];
    const float* b_fn     = (const float*)d_in[4];
    const float* w_g      = (const float*)d_in[5];
    const float* b_g      = (const float*)d_in[6];
    float* out = (float*)d_out;

    const size_t NN  = (size_t)4096 * 4096;
    const size_t XTP = (size_t)4352 * 4096;     // padded to 17 col-tiles of 256
    u16* Sb  = (u16*)d_ws;                      // 67.1 MB
    u16* x0T = Sb + 2 * NN;                     // 35.7 MB each (padded)
    u16* y1T = x0T + XTP;
    u16* y2T = y1T + XTP;
    u16* y3T = y2T + XTP;
    u16* y4T = y3T + XTP;
    u16* u_t = y4T + XTP;                       // [bn][o'] bf16, 33.6 MB
    u16* WT_fn = u_t + (size_t)262144 * 64;     // 128*384 u16
    u16* WT_g  = WT_fn + 128 * 384;             // 64*384 u16
    u16* S0b = Sb;
    u16* S1b = Sb + NN;

    const dim3 g1(32, 17, 1);                   // single GEMM  (544 blocks)
    const dim3 g2(32, 17, 2);                   // fused pair   (1088 blocks)

    cvt_bf16_kernel<<<32768, 256, 0, stream>>>(supports, Sb);
    build_x0_inputs<<<128, 256, 0, stream>>>(inputs, x0T);
    build_x0_state<<<dim3(64, 64), 256, 0, stream>>>(hx, x0T);
    wt_prep<<<192, 256, 0, stream>>>(w_fn, WT_fn, 128);
    wt_prep<<<96, 256, 0, stream>>>(w_g, WT_g, 64);
    // gconv fn diffusion: y1 = S0@x0; {y2 = 2*S0@y1 - x0, y3 = S1@y1}; y4 = 2*S1@y3 - y1
    gemm128_kernel<<<g1, 512, 0, stream>>>(S0b, nullptr, x0T, y1T, nullptr, nullptr, nullptr);
    gemm128_kernel<<<g2, 512, 0, stream>>>(S0b, S1b, y1T, y2T, y3T, x0T, nullptr);
    gemm128_kernel<<<g1, 512, 0, stream>>>(S1b, nullptr, y3T, y4T, nullptr, y1T, nullptr);
    // r,u gates (MFMA): r*hx into x0T state rows, u into u_t
    proj_fn_kernel<<<dim3(32, 64), 256, 0, stream>>>(x0T, y1T, y2T, y3T, y4T,
                                                     WT_fn, b_fn, hx, u_t, x0T);
    // gconv g diffusion
    gemm128_kernel<<<g1, 512, 0, stream>>>(S0b, nullptr, x0T, y1T, nullptr, nullptr, nullptr);
    gemm128_kernel<<<g2, 512, 0, stream>>>(S0b, S1b, y1T, y2T, y3T, x0T, nullptr);
    gemm128_kernel<<<g1, 512, 0, stream>>>(S1b, nullptr, y3T, y4T, nullptr, y1T, nullptr);
    // c = tanh(...), out = u*hx + (1-u)*c
    proj_g_kernel<<<dim3(32, 64), 256, 0, stream>>>(x0T, y1T, y2T, y3T, y4T,
                                                    WT_g, b_g, hx, u_t, out);
}

// Round 5
// 1862.587 us; speedup vs baseline: 1.0779x; 1.0779x over previous
//
#include <hip/hip_runtime.h>

// DCGRU cell, MI355X gfx950.  N=4096, B=64, IN_DIM=2, UNITS=64, K=2, NSUP=2,
// M=5, IN_SZ=66.  Heavy: 8x GEMM Y(4096x4224)=S(4096x4096)@X, bf16 MFMA.
// GEMM v4: 128x256 tile, BK=32, 8 waves (2Mx4N, wave-tile 64x64, acc 64
// AGPR), 2 blocks/CU.  TRIPLE-buffered LDS (3x24KB=72KB), 2-tiles-ahead
// prefetch, counted s_waitcnt vmcnt(3) per iteration -- NO full drain in
// the main loop (T3+T4).  Paired-line LDS layout (uniform 2-way banking,
// 0 conflicts, verified R4) unchanged.  XCD swizzle gives each XCD chunks
// of {4 rb} x {17 cb} so the A working set (4MB) is L2-resident.
// g2+g3 fused via blockIdx.z (share B=y1T).

typedef unsigned short u16;
typedef unsigned int u32;
typedef __attribute__((ext_vector_type(8))) short short8;   // bf16x8 MFMA frag
typedef __attribute__((ext_vector_type(4))) float floatx4;  // MFMA acc
typedef __attribute__((ext_vector_type(4))) u16 u16x4;

__device__ __forceinline__ u16 f2b(float f) {            // fp32 -> bf16 RNE
    u32 x = __float_as_uint(f);
    return (u16)((x + 0x7fffu + ((x >> 16) & 1u)) >> 16);
}
__device__ __forceinline__ float b2f(u16 u) {
    return __uint_as_float(((u32)u) << 16);
}

// async global->LDS, 16B per lane; LDS dest = wave-uniform base + lane*16
#define GLL16(g, l) __builtin_amdgcn_global_load_lds( \
    (const __attribute__((address_space(1))) void*)(g), \
    (__attribute__((address_space(3))) void*)(l), 16, 0, 0)

// ---------------------------------------------------------------- cvt fp32->bf16
__global__ void cvt_bf16_kernel(const float* __restrict__ src, u16* __restrict__ dst) {
    size_t i = ((size_t)blockIdx.x * 256 + threadIdx.x) * 4;
    floatx4 v = *(const floatx4*)&src[i];
    u16x4 p; p[0] = f2b(v[0]); p[1] = f2b(v[1]); p[2] = f2b(v[2]); p[3] = f2b(v[3]);
    *(u16x4*)&dst[i] = p;
}

// ------------------------------------------- x0T rows 0..127  (c=0,1 from inputs)
__global__ void build_x0_inputs(const float* __restrict__ inp, u16* __restrict__ x0T) {
    const int row = blockIdx.x;           // 0..127
    const int c = row >> 6, b = row & 63;
    const int t = threadIdx.x;
    const int n0 = t * 16;
    u16* dst = x0T + (size_t)row * 4096 + n0;
    #pragma unroll
    for (int g = 0; g < 4; ++g) {
        u16x4 pk;
        #pragma unroll
        for (int e = 0; e < 4; ++e) {
            const float* p = &inp[(size_t)b * 8192 + (size_t)(n0 + g * 4 + e) * 2];
            pk[e] = f2b(c ? p[1] : p[0]);
        }
        *(u16x4*)(dst + g * 4) = pk;
    }
}

// ----------------------------- x0T rows 128..4223 from state (hx):  transpose
__global__ void build_x0_state(const float* __restrict__ st, u16* __restrict__ x0T) {
    __shared__ float lds[64 * 68];
    const int t = threadIdx.x;
    const int n0 = blockIdx.x * 64, b = blockIdx.y;
    const float* src = st + (size_t)b * 262144 + (size_t)n0 * 64;
    #pragma unroll
    for (int r = 0; r < 4; ++r) {
        int i = r * 1024 + t * 4;
        floatx4 v = *(const floatx4*)&src[i];
        int nl = i >> 6, j = i & 63;
        *(floatx4*)&lds[nl * 68 + j] = v;
    }
    __syncthreads();
    const int j = t >> 2, q = t & 3;
    u16* dst = x0T + (size_t)((j + 2) * 64 + b) * 4096 + n0 + q * 16;
    #pragma unroll
    for (int g = 0; g < 4; ++g) {
        u16x4 pk;
        #pragma unroll
        for (int e = 0; e < 4; ++e) pk[e] = f2b(lds[(q * 16 + g * 4 + e) * 68 + j]);
        *(u16x4*)(dst + g * 4) = pk;
    }
}

// -------------------------------------------- W^T prep: WT[o][k] bf16, k pad 384
__global__ void wt_prep(const float* __restrict__ W, u16* __restrict__ WT, int O) {
    int idx = blockIdx.x * 256 + threadIdx.x;   // o*384 + k
    int o = idx / 384, k = idx - o * 384;
    if (o < O) WT[idx] = (k < 330) ? f2b(W[(size_t)k * O + o]) : (u16)0;
}

// --------------------------------------------------------------- bf16 MFMA GEMM
// C[m][col] = sum_k A[m][k]*B[col][k]; store YT[col][m]; Y = 2*C - Z if Z.
// Tile 128(M) x 256(N) x K=32 per iter, 128 iters.  8 waves: wr = wave>>2
// (M-half), wc = wave&3 (N-quarter); wave-tile 64x64.
// LDS: 3 buffers of 24KB at 0/24576/49152.  Within a buffer: A region 8KB
// (64 lines of 128B), B region 16KB (128 lines) at +8192.  Line pairing:
// A row r -> line r&63, half r>>6; B row r -> line r&127, half r>>7.
// Byte addr in region: line*128 + ((half*4 + kgrp) ^ (line&7))*16 + (k&7)*2.
// Staging (global_load_lds, linear dest): thread t -> dest bytes t*16;
// line = t>>3, slot = t&7, logical sl = (t&7)^(line&7) ->
// src row = (sl>>2)*half + line, src col = (sl&3)*8.  Uniform 2-way banks.
// Pipeline per iter tt: GLL(tt+2)->bufW | ds_read(tt)<-bufR | lgkmcnt(0) |
// MFMA | vmcnt(3) (tile tt+1 resident; tt+2's 3 loads stay in flight) |
// barrier.  No vmcnt(0) drain in the loop.
__global__ __launch_bounds__(512, 4) void gemm128_kernel(
        const u16* __restrict__ Aa, const u16* __restrict__ Ab,
        const u16* __restrict__ Bp,
        u16* __restrict__ Ya, u16* __restrict__ Yb,
        const u16* __restrict__ Za, const u16* __restrict__ Zb) {
    __shared__ __align__(128) char sm[73728];
    // ---- XCD swizzle with L2-shaped chunks: per XCD, {4 rb} x {17 cb} blocks
    const int nwg = 544 * (int)gridDim.z;
    const int L = (int)blockIdx.x + ((int)blockIdx.y << 5) + (int)blockIdx.z * 544;
    const int vid = (L & 7) * (nwg >> 3) + (L >> 3);     // bijective, nwg%8==0
    const int z = vid / 544;
    const int r = vid - z * 544;
    const int rbg = r / 68;                  // 0..7: group of 4 rb
    const int rem = r - rbg * 68;
    const int cb = rem >> 2;                 // 0..16
    const int rb = (rbg << 2) + (rem & 3);   // 0..31
    const u16* A = z ? Ab : Aa;
    u16*       Y = z ? Yb : Ya;
    const u16* Z = z ? Zb : Za;

    const int t = threadIdx.x;
    const int lane = t & 63, wave = t >> 6;
    const int m16 = lane & 15, quad = lane >> 4;
    const int wr = wave >> 2, wc = wave & 3;

    // ---- staging source (inverse paired-line permutation), linear LDS dest
    const int tl = t >> 3, ts = t & 7;
    const int sa = ts ^ (tl & 7);
    const int rowA = ((sa >> 2) << 6) + tl;          // 0..127
    const int rowB = ((sa >> 2) << 7) + tl;          // 0..63 / 128..191
    const int colS = (sa & 3) << 3;
    const u16* aS  = A  + ((size_t)rb * 128 + rowA) * 4096 + colS;
    const u16* bS0 = Bp + ((size_t)cb * 256 + rowB) * 4096 + colS;
    const u16* bS1 = bS0 + (size_t)64 * 4096;        // B lines 64..127
    const int wl = wave << 10;                       // wave-uniform GLL dest

    // ---- ds_read bases (paired-line addressing)
    const int sx = m16 & 7;
    const char* smA = sm + m16 * 128 + ((((wr << 2) | quad) ^ sx) << 4);
    const char* smB = sm + 8192 + (((wc & 1) << 6) + m16) * 128
                         + ((((wc >> 1) << 2 | quad) ^ sx) << 4);

    floatx4 acc[4][4];
    #pragma unroll
    for (int i = 0; i < 4; ++i)
        #pragma unroll
        for (int j = 0; j < 4; ++j) acc[i][j] = (floatx4)0.f;

    // ---- prologue: tiles 0 -> buf0, 1 -> buf1
    GLL16(aS,       sm + 0             + wl);
    GLL16(bS0,      sm + 8192          + wl);
    GLL16(bS1,      sm + 16384         + wl);
    GLL16(aS  + 32, sm + 24576 + 0     + wl);
    GLL16(bS0 + 32, sm + 24576 + 8192  + wl);
    GLL16(bS1 + 32, sm + 24576 + 16384 + wl);
    asm volatile("s_waitcnt vmcnt(3)" ::: "memory");   // tile 0 resident
    __builtin_amdgcn_s_barrier();

    int Pr = 0, Pw = 49152;                  // read buf (tt%3), write buf ((tt+2)%3)
    for (int tt = 0; tt < 128; ++tt) {
        const int ko = ((tt + 2) & 127) << 5;        // wraps on last iters (quarantined)
        // prefetch tile tt+2 into bufW (2 ahead; DMA overlaps 2 iters of compute)
        GLL16(aS  + ko, sm + Pw + 0     + wl);
        GLL16(bS0 + ko, sm + Pw + 8192  + wl);
        GLL16(bS1 + ko, sm + Pw + 16384 + wl);
        // fragments of tile tt from bufR
        short8 af[4], bf[4];
        #pragma unroll
        for (int i = 0; i < 4; ++i) af[i] = *(const short8*)(smA + Pr + i * 2048);
        #pragma unroll
        for (int j = 0; j < 4; ++j) bf[j] = *(const short8*)(smB + Pr + j * 2048);
        asm volatile("s_waitcnt lgkmcnt(0)" ::: "memory");
        __builtin_amdgcn_sched_barrier(0);
        __builtin_amdgcn_s_setprio(1);
        #pragma unroll
        for (int i = 0; i < 4; ++i)
            #pragma unroll
            for (int j = 0; j < 4; ++j)
                acc[i][j] = __builtin_amdgcn_mfma_f32_16x16x32_bf16(af[i], bf[j], acc[i][j], 0, 0, 0);
        __builtin_amdgcn_s_setprio(0);
        // counted wait: own 3 loads of tile tt+1 complete; tt+2's may fly on
        asm volatile("s_waitcnt vmcnt(3)" ::: "memory");
        __builtin_amdgcn_s_barrier();        // all waves' tt+1 contributions landed
        Pr = (Pr == 49152) ? 0 : Pr + 24576;
        Pw = (Pw == 49152) ? 0 : Pw + 24576;
    }

    // ---- epilogue: C (+ optional 2*C - Z) -> YT[col][row] bf16
    #pragma unroll
    for (int i = 0; i < 4; ++i) {
        const int row = rb * 128 + wr * 64 + i * 16 + quad * 4;
        #pragma unroll
        for (int j = 0; j < 4; ++j) {
            const int col = cb * 256 + wc * 64 + j * 16 + m16;
            const size_t off = (size_t)col * 4096 + row;
            floatx4 v = acc[i][j];
            if (Z) {
                u16x4 zz = *(const u16x4*)(Z + off);
                #pragma unroll
                for (int e = 0; e < 4; ++e) v[e] = 2.f * v[e] - b2f(zz[e]);
            }
            u16x4 pk;
            #pragma unroll
            for (int e = 0; e < 4; ++e) pk[e] = f2b(v[e]);
            *(u16x4*)(Y + off) = pk;
        }
    }
}

// --------------------------------------------------------- proj helpers (X rows)
__device__ __forceinline__ const u16* xrow(int k, int b,
        const u16* x0, const u16* y1, const u16* y2, const u16* y3, const u16* y4) {
    int c = (int)((unsigned)k / 5u);
    int m = k - c * 5;
    if (c > 65) c = 65;                       // pad region: clamp in-bounds (W=0 there)
    const u16* base = (m == 0) ? x0 : (m == 1) ? y1 : (m == 2) ? y2 : (m == 3) ? y3 : y4;
    return base + (size_t)(c * 64 + b) * 4096;
}

__device__ __forceinline__ void ilv(uint4 a, uint4 b, u32* w) {
    // a = 8 bf16 of row k, b = 8 bf16 of row k+1 -> 8 words (k|k+1<<16) per bn
    const u32* ap = (const u32*)&a; const u32* bp = (const u32*)&b;
    #pragma unroll
    for (int i = 0; i < 4; ++i) {
        u32 x = ap[i], y = bp[i];
        w[2 * i]     = (x & 0xffffu) | (y << 16);
        w[2 * i + 1] = (x >> 16) | (y & 0xffff0000u);
    }
}

// ------------------------------------------------- proj fn: MFMA GEMM + gates
__global__ __launch_bounds__(256, 2) void proj_fn_kernel(
        const u16* __restrict__ x0T, const u16* __restrict__ y1T,
        const u16* __restrict__ y2T, const u16* __restrict__ y3T,
        const u16* __restrict__ y4T,
        const u16* __restrict__ WT, const float* __restrict__ bias,
        const float* __restrict__ hx,
        u16* __restrict__ u_t, u16* __restrict__ x0Tw) {
    __shared__ __align__(16) u32 Xs[32 * 132];   // [kp][bn] interleaved, 16.9 KB
    __shared__ __align__(16) u16 Ws[128 * 72];   // [o][k] pad 72, 18.4 KB
    const int t = threadIdx.x;
    const int lane = t & 63, wave = t >> 6;
    const int m16 = lane & 15, quad = lane >> 4;
    const int wr = wave >> 1, wc = wave & 1;
    const int n0 = blockIdx.x * 128, b = blockIdx.y;

    const int kp = t >> 3, sgx = t & 7;          // X staging: kp 0..31, 16 n per sgx
    const int wrow = t >> 1, whalf = t & 1;      // W staging

    floatx4 acc[4][4];
    #pragma unroll
    for (int i = 0; i < 4; ++i)
        #pragma unroll
        for (int j = 0; j < 4; ++j) acc[i][j] = (floatx4)0.f;

    for (int ki = 0; ki < 6; ++ki) {
        const int k0 = ki * 64;
        const u16* pa = xrow(k0 + 2 * kp,     b, x0T, y1T, y2T, y3T, y4T) + n0 + sgx * 16;
        const u16* pb = xrow(k0 + 2 * kp + 1, b, x0T, y1T, y2T, y3T, y4T) + n0 + sgx * 16;
        uint4 a0 = *(const uint4*)pa;
        uint4 a1 = *(const uint4*)(pa + 8);
        uint4 b0 = *(const uint4*)pb;
        uint4 b1 = *(const uint4*)(pb + 8);
        const u16* wsrc = WT + (size_t)wrow * 384 + k0 + whalf * 32;
        uint4 wv[4];
        #pragma unroll
        for (int q = 0; q < 4; ++q) wv[q] = *(const uint4*)(wsrc + q * 8);

        u32 w[16];
        ilv(a0, b0, w);
        ilv(a1, b1, w + 8);
        __syncthreads();                          // prev tile reads done
        u32* xdst = &Xs[kp * 132 + sgx * 16];
        #pragma unroll
        for (int q = 0; q < 4; ++q) *(uint4*)(xdst + q * 4) = *(uint4*)(w + q * 4);
        uint4* wdst = (uint4*)&Ws[wrow * 72 + whalf * 32];
        #pragma unroll
        for (int q = 0; q < 4; ++q) wdst[q] = wv[q];
        __syncthreads();

        #pragma unroll
        for (int ks = 0; ks < 2; ++ks) {
            short8 af[4], bf[4];
            #pragma unroll
            for (int i = 0; i < 4; ++i)
                af[i] = *(const short8*)&Ws[(wr * 64 + i * 16 + m16) * 72 + ks * 32 + quad * 8];
            #pragma unroll
            for (int j = 0; j < 4; ++j) {
                const u32* xp = &Xs[(ks * 16 + quad * 4) * 132 + wc * 64 + j * 16 + m16];
                union { uint4 u; short8 s; } fu;
                fu.u.x = xp[0]; fu.u.y = xp[132]; fu.u.z = xp[264]; fu.u.w = xp[396];
                bf[j] = fu.s;
            }
            #pragma unroll
            for (int i = 0; i < 4; ++i)
                #pragma unroll
                for (int j = 0; j < 4; ++j)
                    acc[i][j] = __builtin_amdgcn_mfma_f32_16x16x32_bf16(af[i], bf[j], acc[i][j], 0, 0, 0);
        }
    }
    // epilogue
    #pragma unroll
    for (int i = 0; i < 4; ++i) {
        const int o0 = wr * 64 + i * 16 + quad * 4;
        floatx4 bz = *(const floatx4*)&bias[o0];
        #pragma unroll
        for (int j = 0; j < 4; ++j) {
            const int bnl = wc * 64 + j * 16 + m16;
            const size_t bn = (size_t)b * 4096 + n0 + bnl;
            floatx4 v = acc[i][j];
            float s[4];
            #pragma unroll
            for (int e = 0; e < 4; ++e) s[e] = 1.f / (1.f + __expf(-(v[e] + bz[e])));
            if (wr == 0) {          // r -> x0T state rows: bf16(r*hx)
                floatx4 hv = *(const floatx4*)&hx[bn * 64 + o0];
                #pragma unroll
                for (int e = 0; e < 4; ++e)
                    x0Tw[(size_t)((o0 + e + 2) * 64 + b) * 4096 + (n0 + bnl)] = f2b(s[e] * hv[e]);
            } else {                // u -> u_t[bn][o-64]
                u16x4 pk;
                #pragma unroll
                for (int e = 0; e < 4; ++e) pk[e] = f2b(s[e]);
                *(u16x4*)&u_t[bn * 64 + (o0 - 64)] = pk;
            }
        }
    }
}

// --------------------------------------- proj g: MFMA GEMM + tanh + GRU output
__global__ __launch_bounds__(256, 2) void proj_g_kernel(
        const u16* __restrict__ x0T, const u16* __restrict__ y1T,
        const u16* __restrict__ y2T, const u16* __restrict__ y3T,
        const u16* __restrict__ y4T,
        const u16* __restrict__ WT, const float* __restrict__ bias,
        const float* __restrict__ hx, const u16* __restrict__ u_t,
        float* __restrict__ out) {
    __shared__ __align__(16) u32 Xs[32 * 132];
    __shared__ __align__(16) u16 Ws[64 * 72];
    const int t = threadIdx.x;
    const int lane = t & 63, wave = t >> 6;
    const int m16 = lane & 15, quad = lane >> 4;
    const int wr = wave >> 1, wc = wave & 1;
    const int n0 = blockIdx.x * 128, b = blockIdx.y;

    const int kp = t >> 3, sgx = t & 7;
    const int wrow = t >> 2, wq = t & 3;

    floatx4 acc[2][4];
    #pragma unroll
    for (int i = 0; i < 2; ++i)
        #pragma unroll
        for (int j = 0; j < 4; ++j) acc[i][j] = (floatx4)0.f;

    for (int ki = 0; ki < 6; ++ki) {
        const int k0 = ki * 64;
        const u16* pa = xrow(k0 + 2 * kp,     b, x0T, y1T, y2T, y3T, y4T) + n0 + sgx * 16;
        const u16* pb = xrow(k0 + 2 * kp + 1, b, x0T, y1T, y2T, y3T, y4T) + n0 + sgx * 16;
        uint4 a0 = *(const uint4*)pa;
        uint4 a1 = *(const uint4*)(pa + 8);
        uint4 b0 = *(const uint4*)pb;
        uint4 b1 = *(const uint4*)(pb + 8);
        const u16* wsrc = WT + (size_t)wrow * 384 + k0 + wq * 16;
        uint4 w0 = *(const uint4*)wsrc;
        uint4 w1 = *(const uint4*)(wsrc + 8);

        u32 w[16];
        ilv(a0, b0, w);
        ilv(a1, b1, w + 8);
        __syncthreads();
        u32* xdst = &Xs[kp * 132 + sgx * 16];
        #pragma unroll
        for (int q = 0; q < 4; ++q) *(uint4*)(xdst + q * 4) = *(uint4*)(w + q * 4);
        *(uint4*)&Ws[wrow * 72 + wq * 16] = w0;
        *(uint4*)&Ws[wrow * 72 + wq * 16 + 8] = w1;
        __syncthreads();

        #pragma unroll
        for (int ks = 0; ks < 2; ++ks) {
            short8 af[2], bf[4];
            #pragma unroll
            for (int i = 0; i < 2; ++i)
                af[i] = *(const short8*)&Ws[(wr * 32 + i * 16 + m16) * 72 + ks * 32 + quad * 8];
            #pragma unroll
            for (int j = 0; j < 4; ++j) {
                const u32* xp = &Xs[(ks * 16 + quad * 4) * 132 + wc * 64 + j * 16 + m16];
                union { uint4 u; short8 s; } fu;
                fu.u.x = xp[0]; fu.u.y = xp[132]; fu.u.z = xp[264]; fu.u.w = xp[396];
                bf[j] = fu.s;
            }
            #pragma unroll
            for (int i = 0; i < 2; ++i)
                #pragma unroll
                for (int j = 0; j < 4; ++j)
                    acc[i][j] = __builtin_amdgcn_mfma_f32_16x16x32_bf16(af[i], bf[j], acc[i][j], 0, 0, 0);
        }
    }
    #pragma unroll
    for (int i = 0; i < 2; ++i) {
        const int o0 = wr * 32 + i * 16 + quad * 4;
        floatx4 bz = *(const floatx4*)&bias[o0];
        #pragma unroll
        for (int j = 0; j < 4; ++j) {
            const int bnl = wc * 64 + j * 16 + m16;
            const size_t bn = (size_t)b * 4096 + n0 + bnl;
            floatx4 v = acc[i][j];
            u16x4 uu = *(const u16x4*)&u_t[bn * 64 + o0];
            floatx4 hv = *(const floatx4*)&hx[bn * 64 + o0];
            floatx4 ov;
            #pragma unroll
            for (int e = 0; e < 4; ++e) {
                float c = tanhf(v[e] + bz[e]);
                float u = b2f(uu[e]);
                ov[e] = u * hv[e] + (1.f - u) * c;
            }
            *(floatx4*)&out[bn * 64 + o0] = ov;
        }
    }
}

// --------------------------------------------------------------------- launch
extern "C" void kernel_launch(void* const* d_in, const int* in_sizes, int n_in,
                              void* d_out, int out_size, void* d_ws, size_t ws_size,
                              hipStream_t stream) {
    (void)in_sizes; (void)n_in; (void)out_size; (void)ws_size;
    const float* inputs   = (const float*)d_in[0];
    const float* hx       = (const float*)d_in[1];
    const float* supports = (const float*)d_in[2];
    const float* w_fn     = (const float*)d_in[3];
    const float* b_fn     = (const float*)d_in[4];
    const float* w_g      = (const float*)d_in[5];
    const float* b_g      = (const float*)d_in[6];
    float* out = (float*)d_out;

    const size_t NN  = (size_t)4096 * 4096;
    const size_t XTP = (size_t)4352 * 4096;     // padded to 17 col-tiles of 256
    u16* Sb  = (u16*)d_ws;                      // 67.1 MB
    u16* x0T = Sb + 2 * NN;                     // 35.7 MB each (padded)
    u16* y1T = x0T + XTP;
    u16* y2T = y1T + XTP;
    u16* y3T = y2T + XTP;
    u16* y4T = y3T + XTP;
    u16* u_t = y4T + XTP;                       // [bn][o'] bf16, 33.6 MB
    u16* WT_fn = u_t + (size_t)262144 * 64;     // 128*384 u16
    u16* WT_g  = WT_fn + 128 * 384;             // 64*384 u16
    u16* S0b = Sb;
    u16* S1b = Sb + NN;

    const dim3 g1(32, 17, 1);                   // single GEMM  (544 blocks)
    const dim3 g2(32, 17, 2);                   // fused pair   (1088 blocks)

    cvt_bf16_kernel<<<32768, 256, 0, stream>>>(supports, Sb);
    build_x0_inputs<<<128, 256, 0, stream>>>(inputs, x0T);
    build_x0_state<<<dim3(64, 64), 256, 0, stream>>>(hx, x0T);
    wt_prep<<<192, 256, 0, stream>>>(w_fn, WT_fn, 128);
    wt_prep<<<96, 256, 0, stream>>>(w_g, WT_g, 64);
    // gconv fn diffusion: y1 = S0@x0; {y2 = 2*S0@y1 - x0, y3 = S1@y1}; y4 = 2*S1@y3 - y1
    gemm128_kernel<<<g1, 512, 0, stream>>>(S0b, nullptr, x0T, y1T, nullptr, nullptr, nullptr);
    gemm128_kernel<<<g2, 512, 0, stream>>>(S0b, S1b, y1T, y2T, y3T, x0T, nullptr);
    gemm128_kernel<<<g1, 512, 0, stream>>>(S1b, nullptr, y3T, y4T, nullptr, y1T, nullptr);
    // r,u gates (MFMA): r*hx into x0T state rows, u into u_t
    proj_fn_kernel<<<dim3(32, 64), 256, 0, stream>>>(x0T, y1T, y2T, y3T, y4T,
                                                     WT_fn, b_fn, hx, u_t, x0T);
    // gconv g diffusion
    gemm128_kernel<<<g1, 512, 0, stream>>>(S0b, nullptr, x0T, y1T, nullptr, nullptr, nullptr);
    gemm128_kernel<<<g2, 512, 0, stream>>>(S0b, S1b, y1T, y2T, y3T, x0T, nullptr);
    gemm128_kernel<<<g1, 512, 0, stream>>>(S1b, nullptr, y3T, y4T, nullptr, y1T, nullptr);
    // c = tanh(...), out = u*hx + (1-u)*c
    proj_g_kernel<<<dim3(32, 64), 256, 0, stream>>>(x0T, y1T, y2T, y3T, y4T,
                                                    WT_g, b_g, hx, u_t, out);
}

// Round 6
// 1658.097 us; speedup vs baseline: 1.2108x; 1.1233x over previous
//
#include <hip/hip_runtime.h>

// DCGRU cell, MI355X gfx950.  N=4096, B=64, IN_DIM=2, UNITS=64, K=2, NSUP=2,
// M=5, IN_SZ=66.  Heavy: 8x GEMM Y(4096x4224)=S(4096x4096)@X, bf16 MFMA.
// GEMM v5: 128 x {256|272} tiles, BK=32, 4 waves (2Mx2N, wave-tile 64x128 /
// fat 64x144, acc[4][8..9]), triple-buffered LDS 75KB, 2 blocks/CU,
// counted vmcnt(6/7) per iter (no drain).  Mixed-N grid: 4224 = 8x256 +
// 8x272 -> singles grid 32x16 = 512 blocks = EXACTLY 2/CU (no straggler
// CUs, no padding read/written).  Paired-line LDS layout (uniform 2-way
// banking): region rows R -> R/2 lines of 128B, slot ^= (line&7);
// global_load_lds keeps linear dest, inverse permutation on global source.
// g2+g3 fused via blockIdx.z (share B=y1T).

typedef unsigned short u16;
typedef unsigned int u32;
typedef __attribute__((ext_vector_type(8))) short short8;   // bf16x8 MFMA frag
typedef __attribute__((ext_vector_type(4))) float floatx4;  // MFMA acc
typedef __attribute__((ext_vector_type(4))) u16 u16x4;

__device__ __forceinline__ u16 f2b(float f) {            // fp32 -> bf16 RNE
    u32 x = __float_as_uint(f);
    return (u16)((x + 0x7fffu + ((x >> 16) & 1u)) >> 16);
}
__device__ __forceinline__ float b2f(u16 u) {
    return __uint_as_float(((u32)u) << 16);
}

// async global->LDS, 16B per lane; LDS dest = wave-uniform base + lane*16
#define GLL16(g, l) __builtin_amdgcn_global_load_lds( \
    (const __attribute__((address_space(1))) void*)(g), \
    (__attribute__((address_space(3))) void*)(l), 16, 0, 0)

// ---------------------------------------------------------------- cvt fp32->bf16
__global__ void cvt_bf16_kernel(const float* __restrict__ src, u16* __restrict__ dst) {
    size_t i = ((size_t)blockIdx.x * 256 + threadIdx.x) * 4;
    floatx4 v = *(const floatx4*)&src[i];
    u16x4 p; p[0] = f2b(v[0]); p[1] = f2b(v[1]); p[2] = f2b(v[2]); p[3] = f2b(v[3]);
    *(u16x4*)&dst[i] = p;
}

// ------------------------------------------- x0T rows 0..127  (c=0,1 from inputs)
__global__ void build_x0_inputs(const float* __restrict__ inp, u16* __restrict__ x0T) {
    const int row = blockIdx.x;           // 0..127
    const int c = row >> 6, b = row & 63;
    const int t = threadIdx.x;
    const int n0 = t * 16;
    u16* dst = x0T + (size_t)row * 4096 + n0;
    #pragma unroll
    for (int g = 0; g < 4; ++g) {
        u16x4 pk;
        #pragma unroll
        for (int e = 0; e < 4; ++e) {
            const float* p = &inp[(size_t)b * 8192 + (size_t)(n0 + g * 4 + e) * 2];
            pk[e] = f2b(c ? p[1] : p[0]);
        }
        *(u16x4*)(dst + g * 4) = pk;
    }
}

// ----------------------------- x0T rows 128..4223 from state (hx):  transpose
__global__ void build_x0_state(const float* __restrict__ st, u16* __restrict__ x0T) {
    __shared__ float lds[64 * 68];
    const int t = threadIdx.x;
    const int n0 = blockIdx.x * 64, b = blockIdx.y;
    const float* src = st + (size_t)b * 262144 + (size_t)n0 * 64;
    #pragma unroll
    for (int r = 0; r < 4; ++r) {
        int i = r * 1024 + t * 4;
        floatx4 v = *(const floatx4*)&src[i];
        int nl = i >> 6, j = i & 63;
        *(floatx4*)&lds[nl * 68 + j] = v;
    }
    __syncthreads();
    const int j = t >> 2, q = t & 3;
    u16* dst = x0T + (size_t)((j + 2) * 64 + b) * 4096 + n0 + q * 16;
    #pragma unroll
    for (int g = 0; g < 4; ++g) {
        u16x4 pk;
        #pragma unroll
        for (int e = 0; e < 4; ++e) pk[e] = f2b(lds[(q * 16 + g * 4 + e) * 68 + j]);
        *(u16x4*)(dst + g * 4) = pk;
    }
}

// -------------------------------------------- W^T prep: WT[o][k] bf16, k pad 384
__global__ void wt_prep(const float* __restrict__ W, u16* __restrict__ WT, int O) {
    int idx = blockIdx.x * 256 + threadIdx.x;   // o*384 + k
    int o = idx / 384, k = idx - o * 384;
    if (o < O) WT[idx] = (k < 330) ? f2b(W[(size_t)k * O + o]) : (u16)0;
}

// --------------------------------------------------------------- bf16 MFMA GEMM
// C[m][col] = sum_k A[m][k]*B[col][k]; store YT[col][m]; Y = 2*C - Z if Z.
// Tile 128(M) x NW(N), NW = 256 (cb<8) or 272 (cb>=8); BK=32, 128 iters.
// 4 waves: wr = wave>>1 (M-half of 128), wc = wave&1 (N-half); wave-tile
// 64 x 128 (fat wc=1: 64 x 144, 9 B-frags).
// LDS: 3 buffers of 25600B at 0/25600/51200 (75KB -> 2 blocks/CU).
// Buffer: A region 8KB (64 lines of 128B; A row r -> line r&63, half r>>6),
// B region at +8192, 17408B capacity (NW/2 lines; col c -> line c%HB,
// half c/HB, HB = NW/2 = 128 or 136).  Byte in region:
// line*128 + ((half*4 + kgrp) ^ (line&7))*16 + (k&7)*2, kgrp = k>>3.
// Uniform 2-way bank aliasing (free) on all ds_read_b128.
// Staging (global_load_lds, linear dest): A 2 GLL + B 4 GLL per wave; fat
// blocks: wave 0 issues 1 extra GLL for B lines 128..135.  Dest line
// L = g*32 + wave*8 + (lane>>3); logical slot sl = (lane&7)^(L&7) ->
// src row/col = (sl>>2)*half_stride + L, k-col = (sl&3)*8.
// Pipeline per iter tt: GLL(tt+2)->bufW | ds_read(tt)<-bufR | MFMA |
// vmcnt(6; 7 for fat wave0) | s_barrier.  No drain in the loop.
__global__ __launch_bounds__(256, 2) void gemm128_kernel(
        const u16* __restrict__ Aa, const u16* __restrict__ Ab,
        const u16* __restrict__ Bp,
        u16* __restrict__ Ya, u16* __restrict__ Yb,
        const u16* __restrict__ Za, const u16* __restrict__ Zb) {
    __shared__ __align__(128) char sm[76800];
    // ---- XCD swizzle (bijective; 512 and 1024 are % 8 == 0)
    const int nwg = 512 * (int)gridDim.z;
    const int L = (int)blockIdx.x + ((int)blockIdx.y << 5) + (int)blockIdx.z * 512;
    const int vid = (L & 7) * (nwg >> 3) + (L >> 3);
    const int z = vid >> 9;
    const int r = vid & 511;
    const int rb = r & 31, cb = r >> 5;
    const int FAT = cb >= 8;
    const int cbase = FAT ? 2048 + (cb - 8) * 272 : cb * 256;
    const int HB = FAT ? 136 : 128;
    const u16* A = z ? Ab : Aa;
    u16*       Y = z ? Yb : Ya;
    const u16* Z = z ? Zb : Za;

    const int t = threadIdx.x;            // 0..255
    const int lane = t & 63, wave = t >> 6;   // 4 waves
    const int m16 = lane & 15, quad = lane >> 4;
    const int wr = wave >> 1, wc = wave & 1;
    const int wl = wave << 10;

    // ---- staging source decode (inverse paired-line permutation)
    const int dl8 = lane >> 3;                       // 0..7
    const int sl = (lane & 7) ^ dl8;
    const int shalf = sl >> 2, kg = sl & 3;
    // A: src row = shalf*64 + (g*32 + wave*8 + dl8)
    const u16* aS0 = A + ((size_t)rb * 128 + shalf * 64 + wave * 8 + dl8) * 4096 + kg * 8;
    const u16* aS1 = aS0 + (size_t)32 * 4096;
    // B: src col = shalf*HB + (g*32 + wave*8 + dl8)
    const u16* bS0 = Bp + ((size_t)cbase + shalf * HB + wave * 8 + dl8) * 4096 + kg * 8;
    const u16* bS1 = bS0 + (size_t)32 * 4096;
    const u16* bS2 = bS0 + (size_t)64 * 4096;
    const u16* bS3 = bS0 + (size_t)96 * 4096;
    // B extra (fat only, wave 0): lines 128..135 -> col = shalf*136 + 128 + dl8
    const u16* bSx = Bp + ((size_t)cbase + shalf * 136 + 128 + dl8) * 4096 + kg * 8;

    #define STAGE(buf, ko) do { \
        GLL16(aS0 + (ko), sm + (buf) + 0     + wl); \
        GLL16(aS1 + (ko), sm + (buf) + 4096  + wl); \
        GLL16(bS0 + (ko), sm + (buf) + 8192  + wl); \
        GLL16(bS1 + (ko), sm + (buf) + 12288 + wl); \
        GLL16(bS2 + (ko), sm + (buf) + 16384 + wl); \
        GLL16(bS3 + (ko), sm + (buf) + 20480 + wl); \
        if (FAT && wave == 0) GLL16(bSx + (ko), sm + (buf) + 24576); \
    } while (0)
    #define VWAIT() do { \
        if (FAT && wave == 0) asm volatile("s_waitcnt vmcnt(7)" ::: "memory"); \
        else                  asm volatile("s_waitcnt vmcnt(6)" ::: "memory"); \
    } while (0)

    // ---- ds_read byte offsets (paired-line + slot swizzle)
    const int sx = m16 & 7;
    const int aBase = m16 * 128 + ((((wr << 2) | quad) ^ sx) << 4);   // + i*2048
    int bOff[9];
    #pragma unroll
    for (int j = 0; j < 9; ++j) {
        int col = wc * 128 + j * 16 + m16;
        int bh = (col >= HB) ? 1 : 0;
        int bl = col - bh * HB;
        bOff[j] = 8192 + bl * 128 + ((((bh << 2) | quad) ^ sx) << 4);
    }
    const int nj9 = FAT && wc;            // this wave has 9 B-frags

    floatx4 acc[4][9];
    #pragma unroll
    for (int i = 0; i < 4; ++i)
        #pragma unroll
        for (int j = 0; j < 9; ++j) acc[i][j] = (floatx4)0.f;

    // ---- prologue: tiles 0 -> buf0, 1 -> buf1
    STAGE(0, 0);
    STAGE(25600, 32);
    VWAIT();                               // tile 0 resident
    __builtin_amdgcn_s_barrier();

    int Pr = 0, Pw = 51200;
    for (int tt = 0; tt < 128; ++tt) {
        const int ko = ((tt + 2) & 127) << 5;        // wraps near end (unused bufs)
        STAGE(Pw, ko);                                // prefetch tile tt+2
        short8 af[4], bf[9];
        #pragma unroll
        for (int i = 0; i < 4; ++i) af[i] = *(const short8*)(sm + Pr + aBase + i * 2048);
        #pragma unroll
        for (int j = 0; j < 8; ++j) bf[j] = *(const short8*)(sm + Pr + bOff[j]);
        if (nj9) bf[8] = *(const short8*)(sm + Pr + bOff[8]);
        #pragma unroll
        for (int i = 0; i < 4; ++i)
            #pragma unroll
            for (int j = 0; j < 8; ++j)
                acc[i][j] = __builtin_amdgcn_mfma_f32_16x16x32_bf16(af[i], bf[j], acc[i][j], 0, 0, 0);
        if (nj9) {
            #pragma unroll
            for (int i = 0; i < 4; ++i)
                acc[i][8] = __builtin_amdgcn_mfma_f32_16x16x32_bf16(af[i], bf[8], acc[i][8], 0, 0, 0);
        }
        VWAIT();                                      // tile tt+1 resident
        __builtin_amdgcn_s_barrier();
        Pr = (Pr == 51200) ? 0 : Pr + 25600;
        Pw = (Pw == 51200) ? 0 : Pw + 25600;
    }

    // ---- epilogue: C (+ optional 2*C - Z) -> YT[col][row] bf16
    #pragma unroll
    for (int i = 0; i < 4; ++i) {
        const int row = rb * 128 + wr * 64 + i * 16 + quad * 4;
        #pragma unroll
        for (int j = 0; j < 9; ++j) {
            if (j < 8 || nj9) {
                const int col = cbase + wc * 128 + j * 16 + m16;
                const size_t off = (size_t)col * 4096 + row;
                floatx4 v = acc[i][j];
                if (Z) {
                    u16x4 zz = *(const u16x4*)(Z + off);
                    #pragma unroll
                    for (int e = 0; e < 4; ++e) v[e] = 2.f * v[e] - b2f(zz[e]);
                }
                u16x4 pk;
                #pragma unroll
                for (int e = 0; e < 4; ++e) pk[e] = f2b(v[e]);
                *(u16x4*)(Y + off) = pk;
            }
        }
    }
    #undef STAGE
    #undef VWAIT
}

// --------------------------------------------------------- proj helpers (X rows)
__device__ __forceinline__ const u16* xrow(int k, int b,
        const u16* x0, const u16* y1, const u16* y2, const u16* y3, const u16* y4) {
    int c = (int)((unsigned)k / 5u);
    int m = k - c * 5;
    if (c > 65) c = 65;                       // pad region: clamp in-bounds (W=0 there)
    const u16* base = (m == 0) ? x0 : (m == 1) ? y1 : (m == 2) ? y2 : (m == 3) ? y3 : y4;
    return base + (size_t)(c * 64 + b) * 4096;
}

__device__ __forceinline__ void ilv(uint4 a, uint4 b, u32* w) {
    // a = 8 bf16 of row k, b = 8 bf16 of row k+1 -> 8 words (k|k+1<<16) per bn
    const u32* ap = (const u32*)&a; const u32* bp = (const u32*)&b;
    #pragma unroll
    for (int i = 0; i < 4; ++i) {
        u32 x = ap[i], y = bp[i];
        w[2 * i]     = (x & 0xffffu) | (y << 16);
        w[2 * i + 1] = (x >> 16) | (y & 0xffff0000u);
    }
}

// ------------------------------------------------- proj fn: MFMA GEMM + gates
__global__ __launch_bounds__(256, 2) void proj_fn_kernel(
        const u16* __restrict__ x0T, const u16* __restrict__ y1T,
        const u16* __restrict__ y2T, const u16* __restrict__ y3T,
        const u16* __restrict__ y4T,
        const u16* __restrict__ WT, const float* __restrict__ bias,
        const float* __restrict__ hx,
        u16* __restrict__ u_t, u16* __restrict__ x0Tw) {
    __shared__ __align__(16) u32 Xs[32 * 132];   // [kp][bn] interleaved, 16.9 KB
    __shared__ __align__(16) u16 Ws[128 * 72];   // [o][k] pad 72, 18.4 KB
    const int t = threadIdx.x;
    const int lane = t & 63, wave = t >> 6;
    const int m16 = lane & 15, quad = lane >> 4;
    const int wr = wave >> 1, wc = wave & 1;
    const int n0 = blockIdx.x * 128, b = blockIdx.y;

    const int kp = t >> 3, sgx = t & 7;          // X staging: kp 0..31, 16 n per sgx
    const int wrow = t >> 1, whalf = t & 1;      // W staging

    floatx4 acc[4][4];
    #pragma unroll
    for (int i = 0; i < 4; ++i)
        #pragma unroll
        for (int j = 0; j < 4; ++j) acc[i][j] = (floatx4)0.f;

    for (int ki = 0; ki < 6; ++ki) {
        const int k0 = ki * 64;
        const u16* pa = xrow(k0 + 2 * kp,     b, x0T, y1T, y2T, y3T, y4T) + n0 + sgx * 16;
        const u16* pb = xrow(k0 + 2 * kp + 1, b, x0T, y1T, y2T, y3T, y4T) + n0 + sgx * 16;
        uint4 a0 = *(const uint4*)pa;
        uint4 a1 = *(const uint4*)(pa + 8);
        uint4 b0 = *(const uint4*)pb;
        uint4 b1 = *(const uint4*)(pb + 8);
        const u16* wsrc = WT + (size_t)wrow * 384 + k0 + whalf * 32;
        uint4 wv[4];
        #pragma unroll
        for (int q = 0; q < 4; ++q) wv[q] = *(const uint4*)(wsrc + q * 8);

        u32 w[16];
        ilv(a0, b0, w);
        ilv(a1, b1, w + 8);
        __syncthreads();                          // prev tile reads done
        u32* xdst = &Xs[kp * 132 + sgx * 16];
        #pragma unroll
        for (int q = 0; q < 4; ++q) *(uint4*)(xdst + q * 4) = *(uint4*)(w + q * 4);
        uint4* wdst = (uint4*)&Ws[wrow * 72 + whalf * 32];
        #pragma unroll
        for (int q = 0; q < 4; ++q) wdst[q] = wv[q];
        __syncthreads();

        #pragma unroll
        for (int ks = 0; ks < 2; ++ks) {
            short8 af[4], bf[4];
            #pragma unroll
            for (int i = 0; i < 4; ++i)
                af[i] = *(const short8*)&Ws[(wr * 64 + i * 16 + m16) * 72 + ks * 32 + quad * 8];
            #pragma unroll
            for (int j = 0; j < 4; ++j) {
                const u32* xp = &Xs[(ks * 16 + quad * 4) * 132 + wc * 64 + j * 16 + m16];
                union { uint4 u; short8 s; } fu;
                fu.u.x = xp[0]; fu.u.y = xp[132]; fu.u.z = xp[264]; fu.u.w = xp[396];
                bf[j] = fu.s;
            }
            #pragma unroll
            for (int i = 0; i < 4; ++i)
                #pragma unroll
                for (int j = 0; j < 4; ++j)
                    acc[i][j] = __builtin_amdgcn_mfma_f32_16x16x32_bf16(af[i], bf[j], acc[i][j], 0, 0, 0);
        }
    }
    // epilogue
    #pragma unroll
    for (int i = 0; i < 4; ++i) {
        const int o0 = wr * 64 + i * 16 + quad * 4;
        floatx4 bz = *(const floatx4*)&bias[o0];
        #pragma unroll
        for (int j = 0; j < 4; ++j) {
            const int bnl = wc * 64 + j * 16 + m16;
            const size_t bn = (size_t)b * 4096 + n0 + bnl;
            floatx4 v = acc[i][j];
            float s[4];
            #pragma unroll
            for (int e = 0; e < 4; ++e) s[e] = 1.f / (1.f + __expf(-(v[e] + bz[e])));
            if (wr == 0) {          // r -> x0T state rows: bf16(r*hx)
                floatx4 hv = *(const floatx4*)&hx[bn * 64 + o0];
                #pragma unroll
                for (int e = 0; e < 4; ++e)
                    x0Tw[(size_t)((o0 + e + 2) * 64 + b) * 4096 + (n0 + bnl)] = f2b(s[e] * hv[e]);
            } else {                // u -> u_t[bn][o-64]
                u16x4 pk;
                #pragma unroll
                for (int e = 0; e < 4; ++e) pk[e] = f2b(s[e]);
                *(u16x4*)&u_t[bn * 64 + (o0 - 64)] = pk;
            }
        }
    }
}

// --------------------------------------- proj g: MFMA GEMM + tanh + GRU output
__global__ __launch_bounds__(256, 2) void proj_g_kernel(
        const u16* __restrict__ x0T, const u16* __restrict__ y1T,
        const u16* __restrict__ y2T, const u16* __restrict__ y3T,
        const u16* __restrict__ y4T,
        const u16* __restrict__ WT, const float* __restrict__ bias,
        const float* __restrict__ hx, const u16* __restrict__ u_t,
        float* __restrict__ out) {
    __shared__ __align__(16) u32 Xs[32 * 132];
    __shared__ __align__(16) u16 Ws[64 * 72];
    const int t = threadIdx.x;
    const int lane = t & 63, wave = t >> 6;
    const int m16 = lane & 15, quad = lane >> 4;
    const int wr = wave >> 1, wc = wave & 1;
    const int n0 = blockIdx.x * 128, b = blockIdx.y;

    const int kp = t >> 3, sgx = t & 7;
    const int wrow = t >> 2, wq = t & 3;

    floatx4 acc[2][4];
    #pragma unroll
    for (int i = 0; i < 2; ++i)
        #pragma unroll
        for (int j = 0; j < 4; ++j) acc[i][j] = (floatx4)0.f;

    for (int ki = 0; ki < 6; ++ki) {
        const int k0 = ki * 64;
        const u16* pa = xrow(k0 + 2 * kp,     b, x0T, y1T, y2T, y3T, y4T) + n0 + sgx * 16;
        const u16* pb = xrow(k0 + 2 * kp + 1, b, x0T, y1T, y2T, y3T, y4T) + n0 + sgx * 16;
        uint4 a0 = *(const uint4*)pa;
        uint4 a1 = *(const uint4*)(pa + 8);
        uint4 b0 = *(const uint4*)pb;
        uint4 b1 = *(const uint4*)(pb + 8);
        const u16* wsrc = WT + (size_t)wrow * 384 + k0 + wq * 16;
        uint4 w0 = *(const uint4*)wsrc;
        uint4 w1 = *(const uint4*)(wsrc + 8);

        u32 w[16];
        ilv(a0, b0, w);
        ilv(a1, b1, w + 8);
        __syncthreads();
        u32* xdst = &Xs[kp * 132 + sgx * 16];
        #pragma unroll
        for (int q = 0; q < 4; ++q) *(uint4*)(xdst + q * 4) = *(uint4*)(w + q * 4);
        *(uint4*)&Ws[wrow * 72 + wq * 16] = w0;
        *(uint4*)&Ws[wrow * 72 + wq * 16 + 8] = w1;
        __syncthreads();

        #pragma unroll
        for (int ks = 0; ks < 2; ++ks) {
            short8 af[2], bf[4];
            #pragma unroll
            for (int i = 0; i < 2; ++i)
                af[i] = *(const short8*)&Ws[(wr * 32 + i * 16 + m16) * 72 + ks * 32 + quad * 8];
            #pragma unroll
            for (int j = 0; j < 4; ++j) {
                const u32* xp = &Xs[(ks * 16 + quad * 4) * 132 + wc * 64 + j * 16 + m16];
                union { uint4 u; short8 s; } fu;
                fu.u.x = xp[0]; fu.u.y = xp[132]; fu.u.z = xp[264]; fu.u.w = xp[396];
                bf[j] = fu.s;
            }
            #pragma unroll
            for (int i = 0; i < 2; ++i)
                #pragma unroll
                for (int j = 0; j < 4; ++j)
                    acc[i][j] = __builtin_amdgcn_mfma_f32_16x16x32_bf16(af[i], bf[j], acc[i][j], 0, 0, 0);
        }
    }
    #pragma unroll
    for (int i = 0; i < 2; ++i) {
        const int o0 = wr * 32 + i * 16 + quad * 4;
        floatx4 bz = *(const floatx4*)&bias[o0];
        #pragma unroll
        for (int j = 0; j < 4; ++j) {
            const int bnl = wc * 64 + j * 16 + m16;
            const size_t bn = (size_t)b * 4096 + n0 + bnl;
            floatx4 v = acc[i][j];
            u16x4 uu = *(const u16x4*)&u_t[bn * 64 + o0];
            floatx4 hv = *(const floatx4*)&hx[bn * 64 + o0];
            floatx4 ov;
            #pragma unroll
            for (int e = 0; e < 4; ++e) {
                float c = tanhf(v[e] + bz[e]);
                float u = b2f(uu[e]);
                ov[e] = u * hv[e] + (1.f - u) * c;
            }
            *(floatx4*)&out[bn * 64 + o0] = ov;
        }
    }
}

// --------------------------------------------------------------------- launch
extern "C" void kernel_launch(void* const* d_in, const int* in_sizes, int n_in,
                              void* d_out, int out_size, void* d_ws, size_t ws_size,
                              hipStream_t stream) {
    (void)in_sizes; (void)n_in; (void)out_size; (void)ws_size;
    const float* inputs   = (const float*)d_in[0];
    const float* hx       = (const float*)d_in[1];
    const float* supports = (const float*)d_in[2];
    const float* w_fn     = (const float*)d_in[3];
    const float* b_fn     = (const float*)d_in[4];
    const float* w_g      = (const float*)d_in[5];
    const float* b_g      = (const float*)d_in[6];
    float* out = (float*)d_out;

    const size_t NN  = (size_t)4096 * 4096;
    const size_t XTP = (size_t)4352 * 4096;     // alloc stride (4224 rows used)
    u16* Sb  = (u16*)d_ws;                      // 67.1 MB
    u16* x0T = Sb + 2 * NN;                     // 35.7 MB each
    u16* y1T = x0T + XTP;
    u16* y2T = y1T + XTP;
    u16* y3T = y2T + XTP;
    u16* y4T = y3T + XTP;
    u16* u_t = y4T + XTP;                       // [bn][o'] bf16, 33.6 MB
    u16* WT_fn = u_t + (size_t)262144 * 64;     // 128*384 u16
    u16* WT_g  = WT_fn + 128 * 384;             // 64*384 u16
    u16* S0b = Sb;
    u16* S1b = Sb + NN;

    const dim3 g1(32, 16, 1);                   // single GEMM  (512 blocks = 2/CU exact)
    const dim3 g2(32, 16, 2);                   // fused pair   (1024 blocks)

    cvt_bf16_kernel<<<32768, 256, 0, stream>>>(supports, Sb);
    build_x0_inputs<<<128, 256, 0, stream>>>(inputs, x0T);
    build_x0_state<<<dim3(64, 64), 256, 0, stream>>>(hx, x0T);
    wt_prep<<<192, 256, 0, stream>>>(w_fn, WT_fn, 128);
    wt_prep<<<96, 256, 0, stream>>>(w_g, WT_g, 64);
    // gconv fn diffusion: y1 = S0@x0; {y2 = 2*S0@y1 - x0, y3 = S1@y1}; y4 = 2*S1@y3 - y1
    gemm128_kernel<<<g1, 256, 0, stream>>>(S0b, nullptr, x0T, y1T, nullptr, nullptr, nullptr);
    gemm128_kernel<<<g2, 256, 0, stream>>>(S0b, S1b, y1T, y2T, y3T, x0T, nullptr);
    gemm128_kernel<<<g1, 256, 0, stream>>>(S1b, nullptr, y3T, y4T, nullptr, y1T, nullptr);
    // r,u gates (MFMA): r*hx into x0T state rows, u into u_t
    proj_fn_kernel<<<dim3(32, 64), 256, 0, stream>>>(x0T, y1T, y2T, y3T, y4T,
                                                     WT_fn, b_fn, hx, u_t, x0T);
    // gconv g diffusion
    gemm128_kernel<<<g1, 256, 0, stream>>>(S0b, nullptr, x0T, y1T, nullptr, nullptr, nullptr);
    gemm128_kernel<<<g2, 256, 0, stream>>>(S0b, S1b, y1T, y2T, y3T, x0T, nullptr);
    gemm128_kernel<<<g1, 256, 0, stream>>>(S1b, nullptr, y3T, y4T, nullptr, y1T, nullptr);
    // c = tanh(...), out = u*hx + (1-u)*c
    proj_g_kernel<<<dim3(32, 64), 256, 0, stream>>>(x0T, y1T, y2T, y3T, y4T,
                                                    WT_g, b_g, hx, u_t, out);
}

// Round 7
// 1559.671 us; speedup vs baseline: 1.2872x; 1.0631x over previous
//
#include <hip/hip_runtime.h>

// DCGRU cell, MI355X gfx950.  N=4096, B=64, IN_DIM=2, UNITS=64, K=2, NSUP=2,
// M=5, IN_SZ=66.  Heavy: 8x GEMM Y(4096x4224)=S(4096x4096)@X, bf16 MFMA.
// GEMM v6: 256 x {256|272} tiles, BK=32, 8 waves (4Mx2N, wave-tile 64x128 /
// fat 64x144, acc[4][8..9]), triple-buffered LDS 3x33792B = 99KB, 1
// block/CU (8 waves/CU), counted per-wave vmcnt(4|5) per iter, no drain.
// Rationale (R6 counters): staging-BW-bound (10.9 TB/s aggregate fetch);
// 256^2 tile cuts staged bytes 1.6x vs 128x256.  Mixed-N grid: 4224 =
// 8x256 + 8x272 -> singles 16x16 = 256 blocks = EXACTLY 1/CU, one round.
// Paired-line LDS layout (uniform 2-way banking): region rows R -> R/2
// lines of 128B, 16B slot ^= (line&7); global_load_lds keeps linear dest,
// inverse permutation on the per-lane global source.
// g2+g3 fused via blockIdx.z (share B=y1T).

typedef unsigned short u16;
typedef unsigned int u32;
typedef __attribute__((ext_vector_type(8))) short short8;   // bf16x8 MFMA frag
typedef __attribute__((ext_vector_type(4))) float floatx4;  // MFMA acc
typedef __attribute__((ext_vector_type(4))) u16 u16x4;

__device__ __forceinline__ u16 f2b(float f) {            // fp32 -> bf16 RNE
    u32 x = __float_as_uint(f);
    return (u16)((x + 0x7fffu + ((x >> 16) & 1u)) >> 16);
}
__device__ __forceinline__ float b2f(u16 u) {
    return __uint_as_float(((u32)u) << 16);
}

// async global->LDS, 16B per lane; LDS dest = wave-uniform base + lane*16
#define GLL16(g, l) __builtin_amdgcn_global_load_lds( \
    (const __attribute__((address_space(1))) void*)(g), \
    (__attribute__((address_space(3))) void*)(l), 16, 0, 0)

// ---------------------------------------------------------------- cvt fp32->bf16
__global__ void cvt_bf16_kernel(const float* __restrict__ src, u16* __restrict__ dst) {
    size_t i = ((size_t)blockIdx.x * 256 + threadIdx.x) * 4;
    floatx4 v = *(const floatx4*)&src[i];
    u16x4 p; p[0] = f2b(v[0]); p[1] = f2b(v[1]); p[2] = f2b(v[2]); p[3] = f2b(v[3]);
    *(u16x4*)&dst[i] = p;
}

// ------------------------------------------- x0T rows 0..127  (c=0,1 from inputs)
__global__ void build_x0_inputs(const float* __restrict__ inp, u16* __restrict__ x0T) {
    const int row = blockIdx.x;           // 0..127
    const int c = row >> 6, b = row & 63;
    const int t = threadIdx.x;
    const int n0 = t * 16;
    u16* dst = x0T + (size_t)row * 4096 + n0;
    #pragma unroll
    for (int g = 0; g < 4; ++g) {
        u16x4 pk;
        #pragma unroll
        for (int e = 0; e < 4; ++e) {
            const float* p = &inp[(size_t)b * 8192 + (size_t)(n0 + g * 4 + e) * 2];
            pk[e] = f2b(c ? p[1] : p[0]);
        }
        *(u16x4*)(dst + g * 4) = pk;
    }
}

// ----------------------------- x0T rows 128..4223 from state (hx):  transpose
__global__ void build_x0_state(const float* __restrict__ st, u16* __restrict__ x0T) {
    __shared__ float lds[64 * 68];
    const int t = threadIdx.x;
    const int n0 = blockIdx.x * 64, b = blockIdx.y;
    const float* src = st + (size_t)b * 262144 + (size_t)n0 * 64;
    #pragma unroll
    for (int r = 0; r < 4; ++r) {
        int i = r * 1024 + t * 4;
        floatx4 v = *(const floatx4*)&src[i];
        int nl = i >> 6, j = i & 63;
        *(floatx4*)&lds[nl * 68 + j] = v;
    }
    __syncthreads();
    const int j = t >> 2, q = t & 3;
    u16* dst = x0T + (size_t)((j + 2) * 64 + b) * 4096 + n0 + q * 16;
    #pragma unroll
    for (int g = 0; g < 4; ++g) {
        u16x4 pk;
        #pragma unroll
        for (int e = 0; e < 4; ++e) pk[e] = f2b(lds[(q * 16 + g * 4 + e) * 68 + j]);
        *(u16x4*)(dst + g * 4) = pk;
    }
}

// -------------------------------------------- W^T prep: WT[o][k] bf16, k pad 384
__global__ void wt_prep(const float* __restrict__ W, u16* __restrict__ WT, int O) {
    int idx = blockIdx.x * 256 + threadIdx.x;   // o*384 + k
    int o = idx / 384, k = idx - o * 384;
    if (o < O) WT[idx] = (k < 330) ? f2b(W[(size_t)k * O + o]) : (u16)0;
}

// --------------------------------------------------------------- bf16 MFMA GEMM
// C[m][col] = sum_k A[m][k]*B[col][k]; store YT[col][m]; Y = 2*C - Z if Z.
// Tile 256(M) x NW(N), NW = 256 (cb<8) or 272 (cb>=8); BK=32, 128 iters.
// 8 waves: wr = wave>>1 (M-quarter of 256), wc = wave&1 (N-half);
// wave-tile 64x128 (fat wc=1: 64x144, 9 B-frags).
// LDS: 3 buffers of 33792B at 0/33792/67584 (99KB -> 1 block/CU).
// Buffer: A region 16KB (128 lines of 128B; A row r -> line r&127, half
// r>>7), B region at +16384, 17408B capacity (NW/2 lines; col c ->
// line c%HB, half c/HB, HB = 128 or 136).  Byte in region:
// line*128 + ((half*4 + kgrp) ^ (line&7))*16 + (k&7)*2, kgrp = k>>3.
// Uniform 2-way bank aliasing (free) on all ds_read_b128.
// Staging: per wave 2 A-GLL + 2 B-GLL (dest line L = g*64 + wave*8 +
// (lane>>3)); fat blocks: wave 0 stages B lines 128..135 with 1 extra GLL.
// Logical slot sl = (lane&7)^(L&7) -> src row/col = (sl>>2)*half_stride+L,
// k-col = (sl&3)*8.  Pipeline per iter tt: STAGE(tt+2)->bufW |
// ds_read(tt)<-bufR | MFMA | vmcnt(4|5) (tile tt+1 resident; tt+2's own
// loads stay in flight) | s_barrier.  No drain in the loop.
__global__ __launch_bounds__(512, 2) void gemm256_kernel(
        const u16* __restrict__ Aa, const u16* __restrict__ Ab,
        const u16* __restrict__ Bp,
        u16* __restrict__ Ya, u16* __restrict__ Yb,
        const u16* __restrict__ Za, const u16* __restrict__ Zb) {
    __shared__ __align__(128) char sm[101376];
    // ---- XCD swizzle (bijective; 256 and 512 are % 8 == 0)
    const int nwg = 256 * (int)gridDim.z;
    const int L = (int)blockIdx.x + ((int)blockIdx.y << 4) + (int)blockIdx.z * 256;
    const int vid = (L & 7) * (nwg >> 3) + (L >> 3);
    const int z = vid >> 8;
    const int r = vid & 255;
    const int rb = r & 15, cb = r >> 4;
    const int FAT = cb >= 8;
    const int cbase = FAT ? 2048 + (cb - 8) * 272 : cb * 256;
    const int HB = FAT ? 136 : 128;
    const u16* A = z ? Ab : Aa;
    u16*       Y = z ? Yb : Ya;
    const u16* Z = z ? Zb : Za;

    const int t = threadIdx.x;            // 0..511
    const int lane = t & 63, wave = t >> 6;   // 8 waves
    const int m16 = lane & 15, quad = lane >> 4;
    const int wr = wave >> 1, wc = wave & 1;  // 4M x 2N
    const int wl = wave << 10;

    // ---- staging source decode (inverse paired-line permutation)
    const int dl8 = lane >> 3;                       // 0..7
    const int sl = (lane & 7) ^ dl8;
    const int shalf = sl >> 2, kg = sl & 3;
    // A: line L = g*64 + wave*8 + dl8 -> src row = shalf*128 + L
    const u16* aS0 = A + ((size_t)rb * 256 + shalf * 128 + wave * 8 + dl8) * 4096 + kg * 8;
    const u16* aS1 = aS0 + (size_t)64 * 4096;
    // B: src col = cbase + shalf*HB + L
    const u16* bS0 = Bp + ((size_t)cbase + shalf * HB + wave * 8 + dl8) * 4096 + kg * 8;
    const u16* bS1 = bS0 + (size_t)64 * 4096;
    // B extra (fat, wave 0 only): lines 128..135 -> col = cbase + shalf*136 + 128 + dl8
    const u16* bSx = Bp + ((size_t)cbase + shalf * 136 + 128 + dl8) * 4096 + kg * 8;

    #define STAGE(buf, ko) do { \
        GLL16(aS0 + (ko), sm + (buf) + 0     + wl); \
        GLL16(aS1 + (ko), sm + (buf) + 8192  + wl); \
        GLL16(bS0 + (ko), sm + (buf) + 16384 + wl); \
        GLL16(bS1 + (ko), sm + (buf) + 24576 + wl); \
        if (FAT && wave == 0) GLL16(bSx + (ko), sm + (buf) + 32768); \
    } while (0)
    #define VWAIT() do { \
        if (FAT && wave == 0) asm volatile("s_waitcnt vmcnt(5)" ::: "memory"); \
        else                  asm volatile("s_waitcnt vmcnt(4)" ::: "memory"); \
    } while (0)

    // ---- ds_read byte offsets (paired-line + slot swizzle)
    const int sx = m16 & 7;
    const int aHalf = wr >> 1;
    const int aBase = ((wr & 1) * 64 + m16) * 128
                    + ((((aHalf << 2) | quad) ^ sx) << 4);      // + i*2048
    int bOff[9];
    #pragma unroll
    for (int j = 0; j < 9; ++j) {
        int col = wc * 128 + j * 16 + m16;
        int bh = (col >= HB) ? 1 : 0;
        int bl = col - bh * HB;
        bOff[j] = 16384 + bl * 128 + ((((bh << 2) | quad) ^ sx) << 4);
    }
    const int nj9 = FAT && wc;            // this wave has 9 B-frags

    floatx4 acc[4][9];
    #pragma unroll
    for (int i = 0; i < 4; ++i)
        #pragma unroll
        for (int j = 0; j < 9; ++j) acc[i][j] = (floatx4)0.f;

    // ---- prologue: tiles 0 -> buf0, 1 -> buf1
    STAGE(0, 0);
    STAGE(33792, 32);
    VWAIT();                               // tile 0 resident
    __builtin_amdgcn_s_barrier();

    int Pr = 0, Pw = 67584;
    for (int tt = 0; tt < 128; ++tt) {
        const int ko = ((tt + 2) & 127) << 5;        // wraps near end (unused bufs)
        STAGE(Pw, ko);                                // prefetch tile tt+2
        short8 af[4], bf[9];
        #pragma unroll
        for (int i = 0; i < 4; ++i) af[i] = *(const short8*)(sm + Pr + aBase + i * 2048);
        #pragma unroll
        for (int j = 0; j < 8; ++j) bf[j] = *(const short8*)(sm + Pr + bOff[j]);
        if (nj9) bf[8] = *(const short8*)(sm + Pr + bOff[8]);
        #pragma unroll
        for (int i = 0; i < 4; ++i)
            #pragma unroll
            for (int j = 0; j < 8; ++j)
                acc[i][j] = __builtin_amdgcn_mfma_f32_16x16x32_bf16(af[i], bf[j], acc[i][j], 0, 0, 0);
        if (nj9) {
            #pragma unroll
            for (int i = 0; i < 4; ++i)
                acc[i][8] = __builtin_amdgcn_mfma_f32_16x16x32_bf16(af[i], bf[8], acc[i][8], 0, 0, 0);
        }
        VWAIT();                                      // tile tt+1 resident
        __builtin_amdgcn_s_barrier();
        Pr = (Pr == 67584) ? 0 : Pr + 33792;
        Pw = (Pw == 67584) ? 0 : Pw + 33792;
    }

    // ---- epilogue: C (+ optional 2*C - Z) -> YT[col][row] bf16
    #pragma unroll
    for (int i = 0; i < 4; ++i) {
        const int row = rb * 256 + wr * 64 + i * 16 + quad * 4;
        #pragma unroll
        for (int j = 0; j < 9; ++j) {
            if (j < 8 || nj9) {
                const int col = cbase + wc * 128 + j * 16 + m16;
                const size_t off = (size_t)col * 4096 + row;
                floatx4 v = acc[i][j];
                if (Z) {
                    u16x4 zz = *(const u16x4*)(Z + off);
                    #pragma unroll
                    for (int e = 0; e < 4; ++e) v[e] = 2.f * v[e] - b2f(zz[e]);
                }
                u16x4 pk;
                #pragma unroll
                for (int e = 0; e < 4; ++e) pk[e] = f2b(v[e]);
                *(u16x4*)(Y + off) = pk;
            }
        }
    }
    #undef STAGE
    #undef VWAIT
}

// --------------------------------------------------------- proj helpers (X rows)
__device__ __forceinline__ const u16* xrow(int k, int b,
        const u16* x0, const u16* y1, const u16* y2, const u16* y3, const u16* y4) {
    int c = (int)((unsigned)k / 5u);
    int m = k - c * 5;
    if (c > 65) c = 65;                       // pad region: clamp in-bounds (W=0 there)
    const u16* base = (m == 0) ? x0 : (m == 1) ? y1 : (m == 2) ? y2 : (m == 3) ? y3 : y4;
    return base + (size_t)(c * 64 + b) * 4096;
}

__device__ __forceinline__ void ilv(uint4 a, uint4 b, u32* w) {
    // a = 8 bf16 of row k, b = 8 bf16 of row k+1 -> 8 words (k|k+1<<16) per bn
    const u32* ap = (const u32*)&a; const u32* bp = (const u32*)&b;
    #pragma unroll
    for (int i = 0; i < 4; ++i) {
        u32 x = ap[i], y = bp[i];
        w[2 * i]     = (x & 0xffffu) | (y << 16);
        w[2 * i + 1] = (x >> 16) | (y & 0xffff0000u);
    }
}

// ------------------------------------------------- proj fn: MFMA GEMM + gates
__global__ __launch_bounds__(256, 2) void proj_fn_kernel(
        const u16* __restrict__ x0T, const u16* __restrict__ y1T,
        const u16* __restrict__ y2T, const u16* __restrict__ y3T,
        const u16* __restrict__ y4T,
        const u16* __restrict__ WT, const float* __restrict__ bias,
        const float* __restrict__ hx,
        u16* __restrict__ u_t, u16* __restrict__ x0Tw) {
    __shared__ __align__(16) u32 Xs[32 * 132];   // [kp][bn] interleaved, 16.9 KB
    __shared__ __align__(16) u16 Ws[128 * 72];   // [o][k] pad 72, 18.4 KB
    const int t = threadIdx.x;
    const int lane = t & 63, wave = t >> 6;
    const int m16 = lane & 15, quad = lane >> 4;
    const int wr = wave >> 1, wc = wave & 1;
    const int n0 = blockIdx.x * 128, b = blockIdx.y;

    const int kp = t >> 3, sgx = t & 7;          // X staging: kp 0..31, 16 n per sgx
    const int wrow = t >> 1, whalf = t & 1;      // W staging

    floatx4 acc[4][4];
    #pragma unroll
    for (int i = 0; i < 4; ++i)
        #pragma unroll
        for (int j = 0; j < 4; ++j) acc[i][j] = (floatx4)0.f;

    for (int ki = 0; ki < 6; ++ki) {
        const int k0 = ki * 64;
        const u16* pa = xrow(k0 + 2 * kp,     b, x0T, y1T, y2T, y3T, y4T) + n0 + sgx * 16;
        const u16* pb = xrow(k0 + 2 * kp + 1, b, x0T, y1T, y2T, y3T, y4T) + n0 + sgx * 16;
        uint4 a0 = *(const uint4*)pa;
        uint4 a1 = *(const uint4*)(pa + 8);
        uint4 b0 = *(const uint4*)pb;
        uint4 b1 = *(const uint4*)(pb + 8);
        const u16* wsrc = WT + (size_t)wrow * 384 + k0 + whalf * 32;
        uint4 wv[4];
        #pragma unroll
        for (int q = 0; q < 4; ++q) wv[q] = *(const uint4*)(wsrc + q * 8);

        u32 w[16];
        ilv(a0, b0, w);
        ilv(a1, b1, w + 8);
        __syncthreads();                          // prev tile reads done
        u32* xdst = &Xs[kp * 132 + sgx * 16];
        #pragma unroll
        for (int q = 0; q < 4; ++q) *(uint4*)(xdst + q * 4) = *(uint4*)(w + q * 4);
        uint4* wdst = (uint4*)&Ws[wrow * 72 + whalf * 32];
        #pragma unroll
        for (int q = 0; q < 4; ++q) wdst[q] = wv[q];
        __syncthreads();

        #pragma unroll
        for (int ks = 0; ks < 2; ++ks) {
            short8 af[4], bf[4];
            #pragma unroll
            for (int i = 0; i < 4; ++i)
                af[i] = *(const short8*)&Ws[(wr * 64 + i * 16 + m16) * 72 + ks * 32 + quad * 8];
            #pragma unroll
            for (int j = 0; j < 4; ++j) {
                const u32* xp = &Xs[(ks * 16 + quad * 4) * 132 + wc * 64 + j * 16 + m16];
                union { uint4 u; short8 s; } fu;
                fu.u.x = xp[0]; fu.u.y = xp[132]; fu.u.z = xp[264]; fu.u.w = xp[396];
                bf[j] = fu.s;
            }
            #pragma unroll
            for (int i = 0; i < 4; ++i)
                #pragma unroll
                for (int j = 0; j < 4; ++j)
                    acc[i][j] = __builtin_amdgcn_mfma_f32_16x16x32_bf16(af[i], bf[j], acc[i][j], 0, 0, 0);
        }
    }
    // epilogue
    #pragma unroll
    for (int i = 0; i < 4; ++i) {
        const int o0 = wr * 64 + i * 16 + quad * 4;
        floatx4 bz = *(const floatx4*)&bias[o0];
        #pragma unroll
        for (int j = 0; j < 4; ++j) {
            const int bnl = wc * 64 + j * 16 + m16;
            const size_t bn = (size_t)b * 4096 + n0 + bnl;
            floatx4 v = acc[i][j];
            float s[4];
            #pragma unroll
            for (int e = 0; e < 4; ++e) s[e] = 1.f / (1.f + __expf(-(v[e] + bz[e])));
            if (wr == 0) {          // r -> x0T state rows: bf16(r*hx)
                floatx4 hv = *(const floatx4*)&hx[bn * 64 + o0];
                #pragma unroll
                for (int e = 0; e < 4; ++e)
                    x0Tw[(size_t)((o0 + e + 2) * 64 + b) * 4096 + (n0 + bnl)] = f2b(s[e] * hv[e]);
            } else {                // u -> u_t[bn][o-64]
                u16x4 pk;
                #pragma unroll
                for (int e = 0; e < 4; ++e) pk[e] = f2b(s[e]);
                *(u16x4*)&u_t[bn * 64 + (o0 - 64)] = pk;
            }
        }
    }
}

// --------------------------------------- proj g: MFMA GEMM + tanh + GRU output
__global__ __launch_bounds__(256, 2) void proj_g_kernel(
        const u16* __restrict__ x0T, const u16* __restrict__ y1T,
        const u16* __restrict__ y2T, const u16* __restrict__ y3T,
        const u16* __restrict__ y4T,
        const u16* __restrict__ WT, const float* __restrict__ bias,
        const float* __restrict__ hx, const u16* __restrict__ u_t,
        float* __restrict__ out) {
    __shared__ __align__(16) u32 Xs[32 * 132];
    __shared__ __align__(16) u16 Ws[64 * 72];
    const int t = threadIdx.x;
    const int lane = t & 63, wave = t >> 6;
    const int m16 = lane & 15, quad = lane >> 4;
    const int wr = wave >> 1, wc = wave & 1;
    const int n0 = blockIdx.x * 128, b = blockIdx.y;

    const int kp = t >> 3, sgx = t & 7;
    const int wrow = t >> 2, wq = t & 3;

    floatx4 acc[2][4];
    #pragma unroll
    for (int i = 0; i < 2; ++i)
        #pragma unroll
        for (int j = 0; j < 4; ++j) acc[i][j] = (floatx4)0.f;

    for (int ki = 0; ki < 6; ++ki) {
        const int k0 = ki * 64;
        const u16* pa = xrow(k0 + 2 * kp,     b, x0T, y1T, y2T, y3T, y4T) + n0 + sgx * 16;
        const u16* pb = xrow(k0 + 2 * kp + 1, b, x0T, y1T, y2T, y3T, y4T) + n0 + sgx * 16;
        uint4 a0 = *(const uint4*)pa;
        uint4 a1 = *(const uint4*)(pa + 8);
        uint4 b0 = *(const uint4*)pb;
        uint4 b1 = *(const uint4*)(pb + 8);
        const u16* wsrc = WT + (size_t)wrow * 384 + k0 + wq * 16;
        uint4 w0 = *(const uint4*)wsrc;
        uint4 w1 = *(const uint4*)(wsrc + 8);

        u32 w[16];
        ilv(a0, b0, w);
        ilv(a1, b1, w + 8);
        __syncthreads();
        u32* xdst = &Xs[kp * 132 + sgx * 16];
        #pragma unroll
        for (int q = 0; q < 4; ++q) *(uint4*)(xdst + q * 4) = *(uint4*)(w + q * 4);
        *(uint4*)&Ws[wrow * 72 + wq * 16] = w0;
        *(uint4*)&Ws[wrow * 72 + wq * 16 + 8] = w1;
        __syncthreads();

        #pragma unroll
        for (int ks = 0; ks < 2; ++ks) {
            short8 af[2], bf[4];
            #pragma unroll
            for (int i = 0; i < 2; ++i)
                af[i] = *(const short8*)&Ws[(wr * 32 + i * 16 + m16) * 72 + ks * 32 + quad * 8];
            #pragma unroll
            for (int j = 0; j < 4; ++j) {
                const u32* xp = &Xs[(ks * 16 + quad * 4) * 132 + wc * 64 + j * 16 + m16];
                union { uint4 u; short8 s; } fu;
                fu.u.x = xp[0]; fu.u.y = xp[132]; fu.u.z = xp[264]; fu.u.w = xp[396];
                bf[j] = fu.s;
            }
            #pragma unroll
            for (int i = 0; i < 2; ++i)
                #pragma unroll
                for (int j = 0; j < 4; ++j)
                    acc[i][j] = __builtin_amdgcn_mfma_f32_16x16x32_bf16(af[i], bf[j], acc[i][j], 0, 0, 0);
        }
    }
    #pragma unroll
    for (int i = 0; i < 2; ++i) {
        const int o0 = wr * 32 + i * 16 + quad * 4;
        floatx4 bz = *(const floatx4*)&bias[o0];
        #pragma unroll
        for (int j = 0; j < 4; ++j) {
            const int bnl = wc * 64 + j * 16 + m16;
            const size_t bn = (size_t)b * 4096 + n0 + bnl;
            floatx4 v = acc[i][j];
            u16x4 uu = *(const u16x4*)&u_t[bn * 64 + o0];
            floatx4 hv = *(const floatx4*)&hx[bn * 64 + o0];
            floatx4 ov;
            #pragma unroll
            for (int e = 0; e < 4; ++e) {
                float c = tanhf(v[e] + bz[e]);
                float u = b2f(uu[e]);
                ov[e] = u * hv[e] + (1.f - u) * c;
            }
            *(floatx4*)&out[bn * 64 + o0] = ov;
        }
    }
}

// --------------------------------------------------------------------- launch
extern "C" void kernel_launch(void* const* d_in, const int* in_sizes, int n_in,
                              void* d_out, int out_size, void* d_ws, size_t ws_size,
                              hipStream_t stream) {
    (void)in_sizes; (void)n_in; (void)out_size; (void)ws_size;
    const float* inputs   = (const float*)d_in[0];
    const float* hx       = (const float*)d_in[1];
    const float* supports = (const float*)d_in[2];
    const float* w_fn     = (const float*)d_in[3];
    const float* b_fn     = (const float*)d_in[4];
    const float* w_g      = (const float*)d_in[5];
    const float* b_g      = (const float*)d_in[6];
    float* out = (float*)d_out;

    const size_t NN  = (size_t)4096 * 4096;
    const size_t XTP = (size_t)4352 * 4096;     // alloc stride (4224 rows used)
    u16* Sb  = (u16*)d_ws;                      // 67.1 MB
    u16* x0T = Sb + 2 * NN;                     // 35.7 MB each
    u16* y1T = x0T + XTP;
    u16* y2T = y1T + XTP;
    u16* y3T = y2T + XTP;
    u16* y4T = y3T + XTP;
    u16* u_t = y4T + XTP;                       // [bn][o'] bf16, 33.6 MB
    u16* WT_fn = u_t + (size_t)262144 * 64;     // 128*384 u16
    u16* WT_g  = WT_fn + 128 * 384;             // 64*384 u16
    u16* S0b = Sb;
    u16* S1b = Sb + NN;

    const dim3 g1(16, 16, 1);                   // single GEMM  (256 blocks = 1/CU exact)
    const dim3 g2(16, 16, 2);                   // fused pair   (512 blocks)

    cvt_bf16_kernel<<<32768, 256, 0, stream>>>(supports, Sb);
    build_x0_inputs<<<128, 256, 0, stream>>>(inputs, x0T);
    build_x0_state<<<dim3(64, 64), 256, 0, stream>>>(hx, x0T);
    wt_prep<<<192, 256, 0, stream>>>(w_fn, WT_fn, 128);
    wt_prep<<<96, 256, 0, stream>>>(w_g, WT_g, 64);
    // gconv fn diffusion: y1 = S0@x0; {y2 = 2*S0@y1 - x0, y3 = S1@y1}; y4 = 2*S1@y3 - y1
    gemm256_kernel<<<g1, 512, 0, stream>>>(S0b, nullptr, x0T, y1T, nullptr, nullptr, nullptr);
    gemm256_kernel<<<g2, 512, 0, stream>>>(S0b, S1b, y1T, y2T, y3T, x0T, nullptr);
    gemm256_kernel<<<g1, 512, 0, stream>>>(S1b, nullptr, y3T, y4T, nullptr, y1T, nullptr);
    // r,u gates (MFMA): r*hx into x0T state rows, u into u_t
    proj_fn_kernel<<<dim3(32, 64), 256, 0, stream>>>(x0T, y1T, y2T, y3T, y4T,
                                                     WT_fn, b_fn, hx, u_t, x0T);
    // gconv g diffusion
    gemm256_kernel<<<g1, 512, 0, stream>>>(S0b, nullptr, x0T, y1T, nullptr, nullptr, nullptr);
    gemm256_kernel<<<g2, 512, 0, stream>>>(S0b, S1b, y1T, y2T, y3T, x0T, nullptr);
    gemm256_kernel<<<g1, 512, 0, stream>>>(S1b, nullptr, y3T, y4T, nullptr, y1T, nullptr);
    // c = tanh(...), out = u*hx + (1-u)*c
    proj_g_kernel<<<dim3(32, 64), 256, 0, stream>>>(x0T, y1T, y2T, y3T, y4T,
                                                    WT_g, b_g, hx, u_t, out);
}